// Round 2
// baseline (326.362 us; speedup 1.0000x reference)
//
#include <hip/hip_runtime.h>
#include <cmath>
#include <cfloat>
#include <climits>

// Match numpy's un-fused f32 arithmetic: matching output is binary, so order
// decisions at the k-th-smallest boundary must agree with the reference.
#pragma clang fp contract(off)

static constexpr int BS = 16;
static constexpr int Qn = 4000;
static constexpr int Cn = 80;
static constexpr int Gn = 128;
static constexpr float kEPS = 1e-8f;

__device__ __forceinline__ bool pless(float av, int ai, float bv, int bi) {
    return (av < bv) || (av == bv && ai < bi);
}

// ---------------------------------------------------------------------------
// Phase A: cost[b][g][q]  ->  out[b][0][g][q]   (unchanged from round 0)
// ---------------------------------------------------------------------------
__global__ __launch_bounds__(256) void kA_cost(
    const float* __restrict__ logits,   // [BS][Qn][Cn]
    const float* __restrict__ boxes,    // [BS][Qn][4] cxcywh
    const int*   __restrict__ labels,   // [BS][Gn]
    const float* __restrict__ tboxes,   // [BS][Gn][4] cxcywh
    float* __restrict__ out)            // [BS][2][Gn][Qn]
{
    const int b  = blockIdx.z;
    const int g0 = blockIdx.y * 16;
    const int q  = blockIdx.x * 256 + threadIdx.x;

    __shared__ float s_cx[16], s_cy[16], s_w[16], s_h[16];
    __shared__ float s_x0[16], s_y0[16], s_x1[16], s_y1[16], s_ar[16];
    __shared__ int   s_lab[16];
    if (threadIdx.x < 16) {
        const int g = g0 + threadIdx.x;
        const float* tb = tboxes + (size_t)(b * Gn + g) * 4;
        float cx = tb[0], cy = tb[1], w = tb[2], h = tb[3];
        float x0 = cx - 0.5f * w, y0 = cy - 0.5f * h;
        float x1 = cx + 0.5f * w, y1 = cy + 0.5f * h;
        s_cx[threadIdx.x] = cx; s_cy[threadIdx.x] = cy;
        s_w[threadIdx.x]  = w;  s_h[threadIdx.x]  = h;
        s_x0[threadIdx.x] = x0; s_y0[threadIdx.x] = y0;
        s_x1[threadIdx.x] = x1; s_y1[threadIdx.x] = y1;
        s_ar[threadIdx.x] = (x1 - x0) * (y1 - y0);
        s_lab[threadIdx.x] = labels[b * Gn + g];
    }
    __syncthreads();
    if (q >= Qn) return;

    const float4 bb = *reinterpret_cast<const float4*>(boxes + (size_t)(b * Qn + q) * 4);
    const float cx = bb.x, cy = bb.y, w = bb.z, h = bb.w;
    const float x0 = cx - 0.5f * w, y0 = cy - 0.5f * h;
    const float x1 = cx + 0.5f * w, y1 = cy + 0.5f * h;
    const float area1 = (x1 - x0) * (y1 - y0);

    const float* lrow = logits + (size_t)(b * Qn + q) * Cn;
    float* orow = out + (size_t)(b * 2) * Gn * Qn + q;   // [b][0][.][q]

    for (int gi = 0; gi < 16; ++gi) {
        const int g = g0 + gi;
        const float l = lrow[s_lab[gi]];
        const float p = 1.0f / (1.0f + expf(-l));
        const float neg = (0.75f * (p * p)) * (-log1pf(-p + kEPS));
        const float pos = (0.25f * ((1.0f - p) * (1.0f - p))) * (-logf(p + kEPS));
        const float cls = pos - neg;
        const float l1 = ((fabsf(cx - s_cx[gi]) + fabsf(cy - s_cy[gi]))
                          + fabsf(w - s_w[gi])) + fabsf(h - s_h[gi]);
        const float ltx = fmaxf(x0, s_x0[gi]), lty = fmaxf(y0, s_y0[gi]);
        const float rbx = fminf(x1, s_x1[gi]), rby = fminf(y1, s_y1[gi]);
        const float iw = fmaxf(rbx - ltx, 0.0f), ih = fmaxf(rby - lty, 0.0f);
        const float inter = iw * ih;
        const float uni = (area1 + s_ar[gi]) - inter;
        const float iou = inter / (uni + kEPS);
        const float cltx = fminf(x0, s_x0[gi]), clty = fminf(y0, s_y0[gi]);
        const float crbx = fmaxf(x1, s_x1[gi]), crby = fmaxf(y1, s_y1[gi]);
        const float cw = fmaxf(crbx - cltx, 0.0f), ch = fmaxf(crby - clty, 0.0f);
        const float areac = cw * ch;
        const float giou = iou - (areac - uni) / (areac + kEPS);

        const float cost = (5.0f * l1 + 2.0f * cls) + 2.0f * (-giou);
        orow[(size_t)g * Qn] = cost;
    }
}

// ---------------------------------------------------------------------------
// Phase B (rewritten): one 64-lane WAVE per (b,g) row. Register-only lists,
// fully static indexing (no scratch), shuffle-butterfly merge, no LDS.
// ---------------------------------------------------------------------------
__device__ __forceinline__ void ins16_pair(float (&cv)[16], int (&ci)[16], float v, int i) {
    bool le[16];
#pragma unroll
    for (int j = 0; j < 16; ++j) le[j] = pless(cv[j], ci[j], v, i);
#pragma unroll
    for (int j = 15; j >= 1; --j) {
        float nv = le[j] ? cv[j] : (le[j - 1] ? v : cv[j - 1]);
        int   ni = le[j] ? ci[j] : (le[j - 1] ? i : ci[j - 1]);
        cv[j] = nv; ci[j] = ni;
    }
    if (!le[0]) { cv[0] = v; ci[0] = i; }
}

__device__ __forceinline__ void ins16_desc(float (&iv)[16], float v) {
    bool ge[16];
#pragma unroll
    for (int j = 0; j < 16; ++j) ge[j] = (iv[j] >= v);
#pragma unroll
    for (int j = 15; j >= 1; --j)
        iv[j] = ge[j] ? iv[j] : (ge[j - 1] ? v : iv[j - 1]);
    if (!ge[0]) iv[0] = v;
}

__device__ __forceinline__ void bitonic16_asc(float (&v)[16], int (&idx)[16]) {
#pragma unroll
    for (int d = 8; d >= 1; d >>= 1) {
#pragma unroll
        for (int i = 0; i < 16; ++i) {
            if ((i & d) == 0) {
                float &va = v[i], &vb = v[i | d];
                int &ia = idx[i], &ib = idx[i | d];
                if (pless(vb, ib, va, ia)) {
                    float tv = va; va = vb; vb = tv;
                    int ti = ia; ia = ib; ib = ti;
                }
            }
        }
    }
}

__device__ __forceinline__ void bitonic16_desc(float (&v)[16]) {
#pragma unroll
    for (int d = 8; d >= 1; d >>= 1) {
#pragma unroll
        for (int i = 0; i < 16; ++i) {
            if ((i & d) == 0) {
                if (v[i | d] > v[i]) { float t = v[i]; v[i] = v[i | d]; v[i | d] = t; }
            }
        }
    }
}

__global__ __launch_bounds__(256) void kB_wave(
    const float* __restrict__ boxes,    // [BS][Qn][4]
    const float* __restrict__ tboxes,   // [BS][Gn][4]
    const float* __restrict__ cost,     // at [b][0][g][q]
    float* __restrict__ thrv,           // [BS*Gn]
    int*   __restrict__ thri)           // [BS*Gn]
{
    const int w    = threadIdx.x >> 6;
    const int lane = threadIdx.x & 63;
    const int r    = blockIdx.x * 4 + w;        // row id in [0, BS*Gn)
    const int b    = r >> 7;                    // Gn = 128
    const int g    = r & (Gn - 1);

    const float* tb = tboxes + (size_t)r * 4;
    const float tcx = tb[0], tcy = tb[1], tw = tb[2], th = tb[3];
    const float tx0 = tcx - 0.5f * tw, ty0 = tcy - 0.5f * th;
    const float tx1 = tcx + 0.5f * tw, ty1 = tcy + 0.5f * th;
    const float tarea = (tx1 - tx0) * (ty1 - ty0);

    const float*  crow = cost + (size_t)(b * 2 * Gn + g) * Qn;
    const float4* brow = reinterpret_cast<const float4*>(boxes) + (size_t)b * Qn;

    float cv[16]; int ci[16]; float iv[16];
#pragma unroll
    for (int j = 0; j < 16; ++j) { cv[j] = INFINITY; ci[j] = INT_MAX; iv[j] = -INFINITY; }

    for (int q = lane; q < Qn; q += 64) {
        const float c = crow[q];
        if (pless(c, q, cv[15], ci[15])) ins16_pair(cv, ci, c, q);

        const float4 bb = brow[q];
        const float x0 = bb.x - 0.5f * bb.z, y0 = bb.y - 0.5f * bb.w;
        const float x1 = bb.x + 0.5f * bb.z, y1 = bb.y + 0.5f * bb.w;
        const float area1 = (x1 - x0) * (y1 - y0);
        const float ltx = fmaxf(x0, tx0), lty = fmaxf(y0, ty0);
        const float rbx = fminf(x1, tx1), rby = fminf(y1, ty1);
        const float iw = fmaxf(rbx - ltx, 0.0f), ih = fmaxf(rby - lty, 0.0f);
        const float inter = iw * ih;
        const float uni = (area1 + tarea) - inter;
        const float iou = inter / (uni + kEPS);
        if (iou > iv[15]) ins16_desc(iv, iou);
    }

    // Butterfly merge across the wave: after 6 rounds every lane holds the
    // row-global 16 smallest (cost,idx) pairs and 16 largest IoUs.
#pragma unroll
    for (int m = 1; m <= 32; m <<= 1) {
        float pv[16]; int pi[16]; float pj[16];
#pragma unroll
        for (int j = 0; j < 16; ++j) {
            pv[j] = __shfl_xor(cv[j], m, 64);
            pi[j] = __shfl_xor(ci[j], m, 64);
            pj[j] = __shfl_xor(iv[j], m, 64);
        }
        // keep 16 smallest of (asc cv) ∪ (asc pv): min with reversed partner
#pragma unroll
        for (int j = 0; j < 16; ++j) {
            if (pless(pv[15 - j], pi[15 - j], cv[j], ci[j])) {
                cv[j] = pv[15 - j]; ci[j] = pi[15 - j];
            }
            iv[j] = fmaxf(iv[j], pj[15 - j]);
        }
        bitonic16_asc(cv, ci);   // bitonic sequence -> sorted asc
        bitonic16_desc(iv);      // bitonic sequence -> sorted desc
    }

    if (lane == 0) {
        float s = 0.0f;
#pragma unroll
        for (int j = 0; j < 10; ++j) s += iv[j];  // descending order, like top_k
        int k = (int)s;                            // trunc toward 0 (s >= 0)
        if (k < 1) k = 1;
        if (k > 16) k = 16;
        // static (unrolled) select of cv[k-1] / ci[k-1] -- NO dynamic indexing
        float tv = cv[0]; int ti = ci[0];
#pragma unroll
        for (int j = 1; j < 16; ++j) {
            const bool sel = (k == j + 1);
            tv = sel ? cv[j] : tv;
            ti = sel ? ci[j] : ti;
        }
        thrv[r] = tv;
        thri[r] = ti;
    }
}

// ---------------------------------------------------------------------------
// Phase C: per anchor column q: matching + (>1 matched) argmin fixup.
// ---------------------------------------------------------------------------
__global__ __launch_bounds__(256) void kC_match(
    const float* __restrict__ outc,     // cost at [b][0][g][q]
    const float* __restrict__ thrv,
    const int*   __restrict__ thri,
    float* __restrict__ out)            // matching at [b][1][g][q]
{
    const int b = blockIdx.y;
    const int q = blockIdx.x * 256 + threadIdx.x;

    __shared__ float s_tv[Gn];
    __shared__ int   s_ti[Gn];
    if (threadIdx.x < Gn) {
        s_tv[threadIdx.x] = thrv[b * Gn + threadIdx.x];
        s_ti[threadIdx.x] = thri[b * Gn + threadIdx.x];
    }
    __syncthreads();
    if (q >= Qn) return;

    const float* crow = outc + (size_t)(b * 2) * Gn * Qn + q;
    unsigned long long m0 = 0, m1 = 0;
    float minc = INFINITY;
    int ming = 0;
    for (int g = 0; g < Gn; ++g) {
        const float c = crow[(size_t)g * Qn];
        const bool mt = (c < s_tv[g]) || (c == s_tv[g] && q <= s_ti[g]);
        if (g < 64) m0 |= (unsigned long long)mt << g;
        else        m1 |= (unsigned long long)mt << (g - 64);
        if (c < minc) { minc = c; ming = g; }   // strict: first argmin
    }
    const int cnt = __popcll(m0) + __popcll(m1);
    const bool fix = (cnt > 1);

    float* mrow = out + (size_t)(b * 2 + 1) * Gn * Qn + q;
    for (int g = 0; g < Gn; ++g) {
        const bool bit = (g < 64) ? ((m0 >> g) & 1ull) : ((m1 >> (g - 64)) & 1ull);
        const bool mt = fix ? (g == ming) : bit;
        mrow[(size_t)g * Qn] = mt ? 1.0f : 0.0f;
    }
}

// ---------------------------------------------------------------------------
extern "C" void kernel_launch(void* const* d_in, const int* in_sizes, int n_in,
                              void* d_out, int out_size, void* d_ws, size_t ws_size,
                              hipStream_t stream) {
    (void)in_sizes; (void)n_in; (void)out_size; (void)ws_size;
    const float* logits = (const float*)d_in[0];
    const float* boxes  = (const float*)d_in[1];
    const int*   labels = (const int*)d_in[2];
    const float* tboxes = (const float*)d_in[3];
    float* out = (float*)d_out;

    float* thrv = (float*)d_ws;                                   // [BS*Gn]
    int*   thri = (int*)((char*)d_ws + (size_t)BS * Gn * sizeof(float));

    dim3 gA((Qn + 255) / 256, Gn / 16, BS);
    kA_cost<<<gA, 256, 0, stream>>>(logits, boxes, labels, tboxes, out);

    dim3 gB((BS * Gn) / 4);   // 4 waves per block, one row per wave
    kB_wave<<<gB, 256, 0, stream>>>(boxes, tboxes, out, thrv, thri);

    dim3 gC((Qn + 255) / 256, BS);
    kC_match<<<gC, 256, 0, stream>>>(out, thrv, thri, out);
}

// Round 3
// 218.265 us; speedup vs baseline: 1.4953x; 1.4953x over previous
//
#include <hip/hip_runtime.h>
#include <cmath>
#include <cfloat>
#include <climits>

// Match numpy's un-fused f32 arithmetic: matching output is binary, so order
// decisions at the k-th-smallest boundary must agree with the reference.
#pragma clang fp contract(off)

static constexpr int BS = 16;
static constexpr int Qn = 4000;
static constexpr int Cn = 80;
static constexpr int Gn = 128;
static constexpr float kEPS = 1e-8f;

__device__ __forceinline__ bool pless(float av, int ai, float bv, int bi) {
    return (av < bv) || (av == bv && ai < bi);
}

// ---------------------------------------------------------------------------
// Phase A: cost[b][g][q]  ->  out[b][0][g][q]   (unchanged; passes)
// ---------------------------------------------------------------------------
__global__ __launch_bounds__(256) void kA_cost(
    const float* __restrict__ logits,   // [BS][Qn][Cn]
    const float* __restrict__ boxes,    // [BS][Qn][4] cxcywh
    const int*   __restrict__ labels,   // [BS][Gn]
    const float* __restrict__ tboxes,   // [BS][Gn][4] cxcywh
    float* __restrict__ out)            // [BS][2][Gn][Qn]
{
    const int b  = blockIdx.z;
    const int g0 = blockIdx.y * 16;
    const int q  = blockIdx.x * 256 + threadIdx.x;

    __shared__ float s_cx[16], s_cy[16], s_w[16], s_h[16];
    __shared__ float s_x0[16], s_y0[16], s_x1[16], s_y1[16], s_ar[16];
    __shared__ int   s_lab[16];
    if (threadIdx.x < 16) {
        const int g = g0 + threadIdx.x;
        const float* tb = tboxes + (size_t)(b * Gn + g) * 4;
        float cx = tb[0], cy = tb[1], w = tb[2], h = tb[3];
        float x0 = cx - 0.5f * w, y0 = cy - 0.5f * h;
        float x1 = cx + 0.5f * w, y1 = cy + 0.5f * h;
        s_cx[threadIdx.x] = cx; s_cy[threadIdx.x] = cy;
        s_w[threadIdx.x]  = w;  s_h[threadIdx.x]  = h;
        s_x0[threadIdx.x] = x0; s_y0[threadIdx.x] = y0;
        s_x1[threadIdx.x] = x1; s_y1[threadIdx.x] = y1;
        s_ar[threadIdx.x] = (x1 - x0) * (y1 - y0);
        s_lab[threadIdx.x] = labels[b * Gn + g];
    }
    __syncthreads();
    if (q >= Qn) return;

    const float4 bb = *reinterpret_cast<const float4*>(boxes + (size_t)(b * Qn + q) * 4);
    const float cx = bb.x, cy = bb.y, w = bb.z, h = bb.w;
    const float x0 = cx - 0.5f * w, y0 = cy - 0.5f * h;
    const float x1 = cx + 0.5f * w, y1 = cy + 0.5f * h;
    const float area1 = (x1 - x0) * (y1 - y0);

    const float* lrow = logits + (size_t)(b * Qn + q) * Cn;
    float* orow = out + (size_t)(b * 2) * Gn * Qn + q;   // [b][0][.][q]

    for (int gi = 0; gi < 16; ++gi) {
        const int g = g0 + gi;
        const float l = lrow[s_lab[gi]];
        const float p = 1.0f / (1.0f + expf(-l));
        const float neg = (0.75f * (p * p)) * (-log1pf(-p + kEPS));
        const float pos = (0.25f * ((1.0f - p) * (1.0f - p))) * (-logf(p + kEPS));
        const float cls = pos - neg;
        const float l1 = ((fabsf(cx - s_cx[gi]) + fabsf(cy - s_cy[gi]))
                          + fabsf(w - s_w[gi])) + fabsf(h - s_h[gi]);
        const float ltx = fmaxf(x0, s_x0[gi]), lty = fmaxf(y0, s_y0[gi]);
        const float rbx = fminf(x1, s_x1[gi]), rby = fminf(y1, s_y1[gi]);
        const float iw = fmaxf(rbx - ltx, 0.0f), ih = fmaxf(rby - lty, 0.0f);
        const float inter = iw * ih;
        const float uni = (area1 + s_ar[gi]) - inter;
        const float iou = inter / (uni + kEPS);
        const float cltx = fminf(x0, s_x0[gi]), clty = fminf(y0, s_y0[gi]);
        const float crbx = fmaxf(x1, s_x1[gi]), crby = fmaxf(y1, s_y1[gi]);
        const float cw = fmaxf(crbx - cltx, 0.0f), ch = fmaxf(crby - clty, 0.0f);
        const float areac = cw * ch;
        const float giou = iou - (areac - uni) / (areac + kEPS);

        const float cost = (5.0f * l1 + 2.0f * cls) + 2.0f * (-giou);
        orow[(size_t)g * Qn] = cost;
    }
}

// ---------------------------------------------------------------------------
// Phase B v3: 2 waves per (b,g) row. Wave 0: 10-slot (cost,idx) selection.
// Wave 1: 10-slot IoU selection -> k. 10-slot hot loop (k<=10 provably),
// 16-padded lists only for the butterfly merge (proven bitonic16 networks).
// launch_bounds(128,1): full VGPR budget -> no scratch spill.
// ---------------------------------------------------------------------------
__device__ __forceinline__ void ins10_pair(float (&cv)[10], int (&ci)[10], float v, int i) {
    bool le[10];
#pragma unroll
    for (int j = 0; j < 10; ++j) le[j] = pless(cv[j], ci[j], v, i);
#pragma unroll
    for (int j = 9; j >= 1; --j) {
        float nv = le[j] ? cv[j] : (le[j - 1] ? v : cv[j - 1]);
        int   ni = le[j] ? ci[j] : (le[j - 1] ? i : ci[j - 1]);
        cv[j] = nv; ci[j] = ni;
    }
    if (!le[0]) { cv[0] = v; ci[0] = i; }
}

__device__ __forceinline__ void ins10_desc(float (&iv)[10], float v) {
    bool ge[10];
#pragma unroll
    for (int j = 0; j < 10; ++j) ge[j] = (iv[j] >= v);
#pragma unroll
    for (int j = 9; j >= 1; --j)
        iv[j] = ge[j] ? iv[j] : (ge[j - 1] ? v : iv[j - 1]);
    if (!ge[0]) iv[0] = v;
}

__device__ __forceinline__ void bitonic16_asc(float (&v)[16], int (&idx)[16]) {
#pragma unroll
    for (int d = 8; d >= 1; d >>= 1) {
#pragma unroll
        for (int i = 0; i < 16; ++i) {
            if ((i & d) == 0) {
                float &va = v[i], &vb = v[i | d];
                int &ia = idx[i], &ib = idx[i | d];
                if (pless(vb, ib, va, ia)) {
                    float tv = va; va = vb; vb = tv;
                    int ti = ia; ia = ib; ib = ti;
                }
            }
        }
    }
}

__device__ __forceinline__ void bitonic16_desc(float (&v)[16]) {
#pragma unroll
    for (int d = 8; d >= 1; d >>= 1) {
#pragma unroll
        for (int i = 0; i < 16; ++i) {
            if ((i & d) == 0) {
                if (v[i | d] > v[i]) { float t = v[i]; v[i] = v[i | d]; v[i | d] = t; }
            }
        }
    }
}

__global__ __launch_bounds__(128, 1) void kB_split(
    const float* __restrict__ boxes,    // [BS][Qn][4]
    const float* __restrict__ tboxes,   // [BS][Gn][4]
    const float* __restrict__ cost,     // at [b][0][g][q]
    float* __restrict__ thrv,           // [BS*Gn]
    int*   __restrict__ thri)           // [BS*Gn]
{
    const int lane = threadIdx.x & 63;
    const int wid  = threadIdx.x >> 6;          // 0: cost selection, 1: iou
    const int r    = blockIdx.x;                // row id in [0, BS*Gn)
    const int b    = r >> 7;                    // Gn = 128
    const int g    = r & (Gn - 1);

    __shared__ int s_k;

    float cw16[16]; int ci16[16];               // wave0 merged result

    if (wid == 0) {
        // ---- cost (val,idx) top-10 ----
        float cv[10]; int ci[10];
#pragma unroll
        for (int j = 0; j < 10; ++j) { cv[j] = INFINITY; ci[j] = INT_MAX; }

        const float* crow = cost + (size_t)(b * 2 * Gn + g) * Qn;
#pragma unroll 1
        for (int it = 0; it < 16; ++it) {
            const int q0 = it * 256 + lane * 4;
            if (q0 < Qn) {
                const float4 c4 = *reinterpret_cast<const float4*>(crow + q0);
                ins10_pair(cv, ci, c4.x, q0);
                ins10_pair(cv, ci, c4.y, q0 + 1);
                ins10_pair(cv, ci, c4.z, q0 + 2);
                ins10_pair(cv, ci, c4.w, q0 + 3);
            }
        }
#pragma unroll
        for (int j = 0; j < 16; ++j) {
            cw16[j] = (j < 10) ? cv[j] : INFINITY;
            ci16[j] = (j < 10) ? ci[j] : INT_MAX;
        }
        // butterfly: every lane ends with the row-global sorted 16 smallest
#pragma unroll
        for (int m = 1; m <= 32; m <<= 1) {
            float tv[16]; int ti[16];
#pragma unroll
            for (int j = 0; j < 16; ++j) {
                tv[j] = __shfl_xor(cw16[15 - j], m, 64);
                ti[j] = __shfl_xor(ci16[15 - j], m, 64);
            }
#pragma unroll
            for (int j = 0; j < 16; ++j) {
                if (pless(tv[j], ti[j], cw16[j], ci16[j])) {
                    cw16[j] = tv[j]; ci16[j] = ti[j];
                }
            }
            bitonic16_asc(cw16, ci16);
        }
    } else {
        // ---- IoU top-10 -> k ----
        const float* tb = tboxes + (size_t)r * 4;
        const float tcx = tb[0], tcy = tb[1], tw = tb[2], th = tb[3];
        const float tx0 = tcx - 0.5f * tw, ty0 = tcy - 0.5f * th;
        const float tx1 = tcx + 0.5f * tw, ty1 = tcy + 0.5f * th;
        const float tarea = (tx1 - tx0) * (ty1 - ty0);

        const float4* brow = reinterpret_cast<const float4*>(boxes) + (size_t)b * Qn;

        float iv[10];
#pragma unroll
        for (int j = 0; j < 10; ++j) iv[j] = -INFINITY;

#pragma unroll 1
        for (int it = 0; it < 16; ++it) {
            const int q0 = it * 256 + lane * 4;
            if (q0 < Qn) {
#pragma unroll
                for (int e = 0; e < 4; ++e) {
                    const float4 bb = brow[q0 + e];
                    const float x0 = bb.x - 0.5f * bb.z, y0 = bb.y - 0.5f * bb.w;
                    const float x1 = bb.x + 0.5f * bb.z, y1 = bb.y + 0.5f * bb.w;
                    const float area1 = (x1 - x0) * (y1 - y0);
                    const float ltx = fmaxf(x0, tx0), lty = fmaxf(y0, ty0);
                    const float rbx = fminf(x1, tx1), rby = fminf(y1, ty1);
                    const float iw = fmaxf(rbx - ltx, 0.0f), ih = fmaxf(rby - lty, 0.0f);
                    const float inter = iw * ih;
                    const float uni = (area1 + tarea) - inter;
                    const float iou = inter / (uni + kEPS);
                    ins10_desc(iv, iou);
                }
            }
        }
        float iw16[16];
#pragma unroll
        for (int j = 0; j < 16; ++j) iw16[j] = (j < 10) ? iv[j] : -INFINITY;
#pragma unroll
        for (int m = 1; m <= 32; m <<= 1) {
            float tv[16];
#pragma unroll
            for (int j = 0; j < 16; ++j) tv[j] = __shfl_xor(iw16[15 - j], m, 64);
#pragma unroll
            for (int j = 0; j < 16; ++j) iw16[j] = fmaxf(iw16[j], tv[j]);
            bitonic16_desc(iw16);
        }
        if (lane == 0) {
            float s = 0.0f;
#pragma unroll
            for (int j = 0; j < 10; ++j) s += iw16[j];  // descending, like top_k
            int k = (int)s;                              // trunc (s >= 0)
            if (k < 1) k = 1;
            if (k > 10) k = 10;
            s_k = k;
        }
    }

    __syncthreads();   // convergent: both waves reach exactly here

    if (threadIdx.x == 0) {
        const int k = s_k;
        // static (unrolled) select of cw16[k-1] / ci16[k-1] -- no dynamic index
        float tv = cw16[0]; int ti = ci16[0];
#pragma unroll
        for (int j = 1; j < 10; ++j) {
            const bool sel = (k == j + 1);
            tv = sel ? cw16[j] : tv;
            ti = sel ? ci16[j] : ti;
        }
        thrv[r] = tv;
        thri[r] = ti;
    }
}

// ---------------------------------------------------------------------------
// Phase C: per anchor column q: matching + (>1 matched) argmin fixup.
// ---------------------------------------------------------------------------
__global__ __launch_bounds__(256) void kC_match(
    const float* __restrict__ outc,     // cost at [b][0][g][q]
    const float* __restrict__ thrv,
    const int*   __restrict__ thri,
    float* __restrict__ out)            // matching at [b][1][g][q]
{
    const int b = blockIdx.y;
    const int q = blockIdx.x * 256 + threadIdx.x;

    __shared__ float s_tv[Gn];
    __shared__ int   s_ti[Gn];
    if (threadIdx.x < Gn) {
        s_tv[threadIdx.x] = thrv[b * Gn + threadIdx.x];
        s_ti[threadIdx.x] = thri[b * Gn + threadIdx.x];
    }
    __syncthreads();
    if (q >= Qn) return;

    const float* crow = outc + (size_t)(b * 2) * Gn * Qn + q;
    unsigned long long m0 = 0, m1 = 0;
    float minc = INFINITY;
    int ming = 0;
    for (int g = 0; g < Gn; ++g) {
        const float c = crow[(size_t)g * Qn];
        const bool mt = (c < s_tv[g]) || (c == s_tv[g] && q <= s_ti[g]);
        if (g < 64) m0 |= (unsigned long long)mt << g;
        else        m1 |= (unsigned long long)mt << (g - 64);
        if (c < minc) { minc = c; ming = g; }   // strict: first argmin
    }
    const int cnt = __popcll(m0) + __popcll(m1);
    const bool fix = (cnt > 1);

    float* mrow = out + (size_t)(b * 2 + 1) * Gn * Qn + q;
    for (int g = 0; g < Gn; ++g) {
        const bool bit = (g < 64) ? ((m0 >> g) & 1ull) : ((m1 >> (g - 64)) & 1ull);
        const bool mt = fix ? (g == ming) : bit;
        mrow[(size_t)g * Qn] = mt ? 1.0f : 0.0f;
    }
}

// ---------------------------------------------------------------------------
extern "C" void kernel_launch(void* const* d_in, const int* in_sizes, int n_in,
                              void* d_out, int out_size, void* d_ws, size_t ws_size,
                              hipStream_t stream) {
    (void)in_sizes; (void)n_in; (void)out_size; (void)ws_size;
    const float* logits = (const float*)d_in[0];
    const float* boxes  = (const float*)d_in[1];
    const int*   labels = (const int*)d_in[2];
    const float* tboxes = (const float*)d_in[3];
    float* out = (float*)d_out;

    float* thrv = (float*)d_ws;                                   // [BS*Gn]
    int*   thri = (int*)((char*)d_ws + (size_t)BS * Gn * sizeof(float));

    dim3 gA((Qn + 255) / 256, Gn / 16, BS);
    kA_cost<<<gA, 256, 0, stream>>>(logits, boxes, labels, tboxes, out);

    dim3 gB(BS * Gn);   // one row per block, 2 waves per row
    kB_split<<<gB, 128, 0, stream>>>(boxes, tboxes, out, thrv, thri);

    dim3 gC((Qn + 255) / 256, BS);
    kC_match<<<gC, 256, 0, stream>>>(out, thrv, thri, out);
}

// Round 4
// 168.647 us; speedup vs baseline: 1.9352x; 1.2942x over previous
//
#include <hip/hip_runtime.h>
#include <cmath>
#include <cfloat>
#include <climits>

// Match numpy's un-fused f32 arithmetic: matching output is binary, so order
// decisions at the k-th-smallest boundary must agree with the reference.
#pragma clang fp contract(off)

static constexpr int BS = 16;
static constexpr int Qn = 4000;
static constexpr int Cn = 80;
static constexpr int Gn = 128;
static constexpr float kEPS = 1e-8f;

// ---------------------------------------------------------------------------
// Phase A: cost[b][g][q]  ->  out[b][0][g][q]   (unchanged; passes)
// ---------------------------------------------------------------------------
__global__ __launch_bounds__(256) void kA_cost(
    const float* __restrict__ logits,   // [BS][Qn][Cn]
    const float* __restrict__ boxes,    // [BS][Qn][4] cxcywh
    const int*   __restrict__ labels,   // [BS][Gn]
    const float* __restrict__ tboxes,   // [BS][Gn][4] cxcywh
    float* __restrict__ out)            // [BS][2][Gn][Qn]
{
    const int b  = blockIdx.z;
    const int g0 = blockIdx.y * 16;
    const int q  = blockIdx.x * 256 + threadIdx.x;

    __shared__ float s_cx[16], s_cy[16], s_w[16], s_h[16];
    __shared__ float s_x0[16], s_y0[16], s_x1[16], s_y1[16], s_ar[16];
    __shared__ int   s_lab[16];
    if (threadIdx.x < 16) {
        const int g = g0 + threadIdx.x;
        const float* tb = tboxes + (size_t)(b * Gn + g) * 4;
        float cx = tb[0], cy = tb[1], w = tb[2], h = tb[3];
        float x0 = cx - 0.5f * w, y0 = cy - 0.5f * h;
        float x1 = cx + 0.5f * w, y1 = cy + 0.5f * h;
        s_cx[threadIdx.x] = cx; s_cy[threadIdx.x] = cy;
        s_w[threadIdx.x]  = w;  s_h[threadIdx.x]  = h;
        s_x0[threadIdx.x] = x0; s_y0[threadIdx.x] = y0;
        s_x1[threadIdx.x] = x1; s_y1[threadIdx.x] = y1;
        s_ar[threadIdx.x] = (x1 - x0) * (y1 - y0);
        s_lab[threadIdx.x] = labels[b * Gn + g];
    }
    __syncthreads();
    if (q >= Qn) return;

    const float4 bb = *reinterpret_cast<const float4*>(boxes + (size_t)(b * Qn + q) * 4);
    const float cx = bb.x, cy = bb.y, w = bb.z, h = bb.w;
    const float x0 = cx - 0.5f * w, y0 = cy - 0.5f * h;
    const float x1 = cx + 0.5f * w, y1 = cy + 0.5f * h;
    const float area1 = (x1 - x0) * (y1 - y0);

    const float* lrow = logits + (size_t)(b * Qn + q) * Cn;
    float* orow = out + (size_t)(b * 2) * Gn * Qn + q;   // [b][0][.][q]

    for (int gi = 0; gi < 16; ++gi) {
        const int g = g0 + gi;
        const float l = lrow[s_lab[gi]];
        const float p = 1.0f / (1.0f + expf(-l));
        const float neg = (0.75f * (p * p)) * (-log1pf(-p + kEPS));
        const float pos = (0.25f * ((1.0f - p) * (1.0f - p))) * (-logf(p + kEPS));
        const float cls = pos - neg;
        const float l1 = ((fabsf(cx - s_cx[gi]) + fabsf(cy - s_cy[gi]))
                          + fabsf(w - s_w[gi])) + fabsf(h - s_h[gi]);
        const float ltx = fmaxf(x0, s_x0[gi]), lty = fmaxf(y0, s_y0[gi]);
        const float rbx = fminf(x1, s_x1[gi]), rby = fminf(y1, s_y1[gi]);
        const float iw = fmaxf(rbx - ltx, 0.0f), ih = fmaxf(rby - lty, 0.0f);
        const float inter = iw * ih;
        const float uni = (area1 + s_ar[gi]) - inter;
        const float iou = inter / (uni + kEPS);
        const float cltx = fminf(x0, s_x0[gi]), clty = fminf(y0, s_y0[gi]);
        const float crbx = fmaxf(x1, s_x1[gi]), crby = fmaxf(y1, s_y1[gi]);
        const float cw = fmaxf(crbx - cltx, 0.0f), ch = fmaxf(crby - clty, 0.0f);
        const float areac = cw * ch;
        const float giou = iou - (areac - uni) / (areac + kEPS);

        const float cost = (5.0f * l1 + 2.0f * cls) + 2.0f * (-giou);
        orow[(size_t)g * Qn] = cost;
    }
}

// ---------------------------------------------------------------------------
// Phase B v4: 4 waves per (b,g) row. Waves 0,1: cost top-10 as packed u64
// (sortable-float<<32 | q) -> single u64 compare per slot. Waves 2,3: IoU
// top-10 (f32). Wave-internal shuffle butterfly + one LDS pair-merge.
// ---------------------------------------------------------------------------
__device__ __forceinline__ unsigned long long pack_ci(float c, int q) {
    const unsigned int u = __float_as_uint(c + 0.0f);       // -0.0 -> +0.0
    const unsigned int s = (u & 0x80000000u) ? ~u : (u | 0x80000000u);
    return ((unsigned long long)s << 32) | (unsigned int)q;
}

__device__ __forceinline__ unsigned long long shfl_xor_u64(unsigned long long v, int m) {
    const int lo = __shfl_xor((int)(unsigned int)v, m, 64);
    const int hi = __shfl_xor((int)(unsigned int)(v >> 32), m, 64);
    return ((unsigned long long)(unsigned int)hi << 32) | (unsigned int)lo;
}

__device__ __forceinline__ void ins10_u64(unsigned long long (&kv)[10], unsigned long long nk) {
    bool le[10];
#pragma unroll
    for (int j = 0; j < 10; ++j) le[j] = (kv[j] < nk);
#pragma unroll
    for (int j = 9; j >= 1; --j)
        kv[j] = le[j] ? kv[j] : (le[j - 1] ? nk : kv[j - 1]);
    if (!le[0]) kv[0] = nk;
}

__device__ __forceinline__ void ins10_desc(float (&iv)[10], float v) {
    bool ge[10];
#pragma unroll
    for (int j = 0; j < 10; ++j) ge[j] = (iv[j] >= v);
#pragma unroll
    for (int j = 9; j >= 1; --j)
        iv[j] = ge[j] ? iv[j] : (ge[j - 1] ? v : iv[j - 1]);
    if (!ge[0]) iv[0] = v;
}

__device__ __forceinline__ void bitonic16_u64(unsigned long long (&v)[16]) {
#pragma unroll
    for (int d = 8; d >= 1; d >>= 1) {
#pragma unroll
        for (int i = 0; i < 16; ++i) {
            if ((i & d) == 0) {
                if (v[i | d] < v[i]) {
                    unsigned long long t = v[i]; v[i] = v[i | d]; v[i | d] = t;
                }
            }
        }
    }
}

__device__ __forceinline__ void bitonic16_desc(float (&v)[16]) {
#pragma unroll
    for (int d = 8; d >= 1; d >>= 1) {
#pragma unroll
        for (int i = 0; i < 16; ++i) {
            if ((i & d) == 0) {
                if (v[i | d] > v[i]) { float t = v[i]; v[i] = v[i | d]; v[i | d] = t; }
            }
        }
    }
}

__global__ __launch_bounds__(256) void kB4(
    const float* __restrict__ boxes,    // [BS][Qn][4]
    const float* __restrict__ tboxes,   // [BS][Gn][4]
    const float* __restrict__ cost,     // at [b][0][g][q]
    float* __restrict__ thrv,           // [BS*Gn]
    int*   __restrict__ thri)           // [BS*Gn]
{
    const int lane = threadIdx.x & 63;
    const int wid  = threadIdx.x >> 6;          // 0,1: cost; 2,3: iou
    const int r    = blockIdx.x;                // row id in [0, BS*Gn)
    const int b    = r >> 7;                    // Gn = 128
    const int g    = r & (Gn - 1);

    __shared__ unsigned long long s_c16[16];
    __shared__ float s_i16[16];
    __shared__ int s_k;

    unsigned long long cm16[16];
    float im16[16];

    if (wid < 2) {
        // ---- cost (packed u64) top-10 over this wave's interleaved half ----
        unsigned long long kv[10];
#pragma unroll
        for (int j = 0; j < 10; ++j) kv[j] = ~0ull;

        const float* crow = cost + (size_t)(b * 2 * Gn + g) * Qn;
        const int base = wid * 256 + lane * 4;
#pragma unroll
        for (int it = 0; it < 8; ++it) {
            const int q0 = it * 512 + base;
            if (q0 < Qn) {
                const float4 c4 = *reinterpret_cast<const float4*>(crow + q0);
                ins10_u64(kv, pack_ci(c4.x, q0));
                ins10_u64(kv, pack_ci(c4.y, q0 + 1));
                ins10_u64(kv, pack_ci(c4.z, q0 + 2));
                ins10_u64(kv, pack_ci(c4.w, q0 + 3));
            }
        }
#pragma unroll
        for (int j = 0; j < 16; ++j) cm16[j] = (j < 10) ? kv[j] : ~0ull;
        // wave-internal butterfly: all lanes end with the wave-global sorted 16
#pragma unroll
        for (int m = 1; m <= 32; m <<= 1) {
            unsigned long long t[16];
#pragma unroll
            for (int j = 0; j < 16; ++j) t[j] = shfl_xor_u64(cm16[15 - j], m);
#pragma unroll
            for (int j = 0; j < 16; ++j) if (t[j] < cm16[j]) cm16[j] = t[j];
            bitonic16_u64(cm16);
        }
    } else {
        // ---- IoU top-10 over this wave's interleaved half ----
        const float* tb = tboxes + (size_t)r * 4;
        const float tcx = tb[0], tcy = tb[1], tw = tb[2], th = tb[3];
        const float tx0 = tcx - 0.5f * tw, ty0 = tcy - 0.5f * th;
        const float tx1 = tcx + 0.5f * tw, ty1 = tcy + 0.5f * th;
        const float tarea = (tx1 - tx0) * (ty1 - ty0);

        const float4* brow = reinterpret_cast<const float4*>(boxes) + (size_t)b * Qn;

        float iv[10];
#pragma unroll
        for (int j = 0; j < 10; ++j) iv[j] = -INFINITY;

        const int base = (wid - 2) * 256 + lane * 4;
#pragma unroll
        for (int it = 0; it < 8; ++it) {
            const int q0 = it * 512 + base;
            if (q0 < Qn) {
#pragma unroll
                for (int e = 0; e < 4; ++e) {
                    const float4 bb = brow[q0 + e];
                    const float x0 = bb.x - 0.5f * bb.z, y0 = bb.y - 0.5f * bb.w;
                    const float x1 = bb.x + 0.5f * bb.z, y1 = bb.y + 0.5f * bb.w;
                    const float area1 = (x1 - x0) * (y1 - y0);
                    const float ltx = fmaxf(x0, tx0), lty = fmaxf(y0, ty0);
                    const float rbx = fminf(x1, tx1), rby = fminf(y1, ty1);
                    const float iw = fmaxf(rbx - ltx, 0.0f), ih = fmaxf(rby - lty, 0.0f);
                    const float inter = iw * ih;
                    const float uni = (area1 + tarea) - inter;
                    const float iou = inter / (uni + kEPS);
                    ins10_desc(iv, iou);
                }
            }
        }
#pragma unroll
        for (int j = 0; j < 16; ++j) im16[j] = (j < 10) ? iv[j] : -INFINITY;
#pragma unroll
        for (int m = 1; m <= 32; m <<= 1) {
            float t[16];
#pragma unroll
            for (int j = 0; j < 16; ++j) t[j] = __shfl_xor(im16[15 - j], m, 64);
#pragma unroll
            for (int j = 0; j < 16; ++j) im16[j] = fmaxf(im16[j], t[j]);
            bitonic16_desc(im16);
        }
    }

    // publish wave1 / wave3 results (static unrolled single-lane writes)
    if (wid == 1 && lane == 0) {
#pragma unroll
        for (int j = 0; j < 16; ++j) s_c16[j] = cm16[j];
    }
    if (wid == 3 && lane == 0) {
#pragma unroll
        for (int j = 0; j < 16; ++j) s_i16[j] = im16[j];
    }
    __syncthreads();

    if (wid == 0) {
        // pair-merge cost lists (broadcast LDS reads, conflict-free)
#pragma unroll
        for (int j = 0; j < 16; ++j) {
            const unsigned long long t = s_c16[15 - j];
            if (t < cm16[j]) cm16[j] = t;
        }
        bitonic16_u64(cm16);
    }
    if (wid == 2) {
#pragma unroll
        for (int j = 0; j < 16; ++j) im16[j] = fmaxf(im16[j], s_i16[15 - j]);
        bitonic16_desc(im16);
        if (lane == 0) {
            float s = 0.0f;
#pragma unroll
            for (int j = 0; j < 10; ++j) s += im16[j];  // descending, like top_k
            int k = (int)s;                              // trunc (s >= 0)
            if (k < 1) k = 1;
            if (k > 10) k = 10;
            s_k = k;
        }
    }
    __syncthreads();

    if (threadIdx.x == 0) {
        const int k = s_k;
        unsigned long long key = cm16[0];
#pragma unroll
        for (int j = 1; j < 10; ++j) key = (k == j + 1) ? cm16[j] : key;
        const unsigned int s = (unsigned int)(key >> 32);
        thrv[r] = __uint_as_float((s & 0x80000000u) ? (s ^ 0x80000000u) : ~s);
        thri[r] = (int)(unsigned int)key;
    }
}

// ---------------------------------------------------------------------------
// Phase C: per anchor column q: matching + (>1 matched) argmin fixup.
// ---------------------------------------------------------------------------
__global__ __launch_bounds__(256) void kC_match(
    const float* __restrict__ outc,     // cost at [b][0][g][q]
    const float* __restrict__ thrv,
    const int*   __restrict__ thri,
    float* __restrict__ out)            // matching at [b][1][g][q]
{
    const int b = blockIdx.y;
    const int q = blockIdx.x * 256 + threadIdx.x;

    __shared__ float s_tv[Gn];
    __shared__ int   s_ti[Gn];
    if (threadIdx.x < Gn) {
        s_tv[threadIdx.x] = thrv[b * Gn + threadIdx.x];
        s_ti[threadIdx.x] = thri[b * Gn + threadIdx.x];
    }
    __syncthreads();
    if (q >= Qn) return;

    const float* crow = outc + (size_t)(b * 2) * Gn * Qn + q;
    unsigned long long m0 = 0, m1 = 0;
    float minc = INFINITY;
    int ming = 0;
    for (int g = 0; g < Gn; ++g) {
        const float c = crow[(size_t)g * Qn];
        const bool mt = (c < s_tv[g]) || (c == s_tv[g] && q <= s_ti[g]);
        if (g < 64) m0 |= (unsigned long long)mt << g;
        else        m1 |= (unsigned long long)mt << (g - 64);
        if (c < minc) { minc = c; ming = g; }   // strict: first argmin
    }
    const int cnt = __popcll(m0) + __popcll(m1);
    const bool fix = (cnt > 1);

    float* mrow = out + (size_t)(b * 2 + 1) * Gn * Qn + q;
    for (int g = 0; g < Gn; ++g) {
        const bool bit = (g < 64) ? ((m0 >> g) & 1ull) : ((m1 >> (g - 64)) & 1ull);
        const bool mt = fix ? (g == ming) : bit;
        mrow[(size_t)g * Qn] = mt ? 1.0f : 0.0f;
    }
}

// ---------------------------------------------------------------------------
extern "C" void kernel_launch(void* const* d_in, const int* in_sizes, int n_in,
                              void* d_out, int out_size, void* d_ws, size_t ws_size,
                              hipStream_t stream) {
    (void)in_sizes; (void)n_in; (void)out_size; (void)ws_size;
    const float* logits = (const float*)d_in[0];
    const float* boxes  = (const float*)d_in[1];
    const int*   labels = (const int*)d_in[2];
    const float* tboxes = (const float*)d_in[3];
    float* out = (float*)d_out;

    float* thrv = (float*)d_ws;                                   // [BS*Gn]
    int*   thri = (int*)((char*)d_ws + (size_t)BS * Gn * sizeof(float));

    dim3 gA((Qn + 255) / 256, Gn / 16, BS);
    kA_cost<<<gA, 256, 0, stream>>>(logits, boxes, labels, tboxes, out);

    dim3 gB(BS * Gn);   // one row per block, 4 waves per row
    kB4<<<gB, 256, 0, stream>>>(boxes, tboxes, out, thrv, thri);

    dim3 gC((Qn + 255) / 256, BS);
    kC_match<<<gC, 256, 0, stream>>>(out, thrv, thri, out);
}

// Round 6
// 141.610 us; speedup vs baseline: 2.3047x; 1.1909x over previous
//
#include <hip/hip_runtime.h>
#include <cmath>
#include <cfloat>
#include <climits>

// Match numpy's un-fused f32 arithmetic: matching output is binary, so order
// decisions at the k-th-smallest boundary must agree with the reference.
#pragma clang fp contract(off)

static constexpr int BS = 16;
static constexpr int Qn = 4000;
static constexpr int Cn = 80;
static constexpr int Gn = 128;
static constexpr float kEPS = 1e-8f;

// Replay-invariance rule (learned round 5): every byte of d_out/d_ws holds
// exactly ONE value per call, identical across calls. No buffer region is
// reused for two different purposes within a call.
//
// d_ws layout: [0,8K) thrv | [8K,16K) thri | [16K, 16K+20.48M) F[b][c][q]

static constexpr size_t kThrvOff = 0;
static constexpr size_t kThriOff = 8 * 1024;
static constexpr size_t kFOff    = 16 * 1024;
static constexpr size_t kFBytes  = (size_t)BS * Cn * Qn * sizeof(float);

__device__ __forceinline__ float focal_cost(float l) {
    const float p = 1.0f / (1.0f + expf(-l));
    const float neg = (0.75f * (p * p)) * (-log1pf(-p + kEPS));
    const float pos = (0.25f * ((1.0f - p) * (1.0f - p))) * (-logf(p + kEPS));
    return pos - neg;
}

// ---------------------------------------------------------------------------
// kP: focal class cost, transposed into d_ws: F[b][c][q].
// Coalesced read of logits, LDS transpose (pad 81 -> conflict-free).
// ---------------------------------------------------------------------------
__global__ __launch_bounds__(256) void kP_focal(
    const float* __restrict__ logits,   // [BS][Qn][Cn]
    float* __restrict__ F)              // [BS][Cn][Qn]
{
    const int b  = blockIdx.y;
    const int q0 = blockIdx.x * 32;
    const int t  = threadIdx.x;

    __shared__ float s_f[32 * 81];      // [ql][c] padded

    const float* src = logits + ((size_t)b * Qn + q0) * Cn;
#pragma unroll
    for (int i = 0; i < 10; ++i) {
        const int idx = t + i * 256;    // < 2560 = 32*80
        const int ql = idx / 80, c = idx % 80;
        s_f[ql * 81 + c] = focal_cost(src[idx]);
    }
    __syncthreads();

    float* dst = F + (size_t)b * Cn * Qn;
#pragma unroll
    for (int i = 0; i < 10; ++i) {
        const int j = t + i * 256;
        const int c = j >> 5, ql = j & 31;
        dst[(size_t)c * Qn + q0 + ql] = s_f[ql * 81 + c];
    }
}

// ---------------------------------------------------------------------------
// kF: fused cost + selection. One 2-wave block per (b,g) row. Streams q:
// class cost (from F, or gathered from logits if USE_F=false) + boxes ->
// L1/IoU/GIoU -> cost (written once to out[b][0]) and in-register top-10
// lists (u64-packed cost, f32 iou). Shuffle butterfly + LDS pair merge.
// ---------------------------------------------------------------------------
__device__ __forceinline__ unsigned long long pack_ci(float c, int q) {
    const unsigned int u = __float_as_uint(c + 0.0f);       // -0.0 -> +0.0
    const unsigned int s = (u & 0x80000000u) ? ~u : (u | 0x80000000u);
    return ((unsigned long long)s << 32) | (unsigned int)q;
}

__device__ __forceinline__ unsigned long long shfl_xor_u64(unsigned long long v, int m) {
    const int lo = __shfl_xor((int)(unsigned int)v, m, 64);
    const int hi = __shfl_xor((int)(unsigned int)(v >> 32), m, 64);
    return ((unsigned long long)(unsigned int)hi << 32) | (unsigned int)lo;
}

__device__ __forceinline__ void ins10_u64(unsigned long long (&kv)[10], unsigned long long nk) {
    bool le[10];
#pragma unroll
    for (int j = 0; j < 10; ++j) le[j] = (kv[j] < nk);
#pragma unroll
    for (int j = 9; j >= 1; --j)
        kv[j] = le[j] ? kv[j] : (le[j - 1] ? nk : kv[j - 1]);
    if (!le[0]) kv[0] = nk;
}

__device__ __forceinline__ void ins10_desc(float (&iv)[10], float v) {
    bool ge[10];
#pragma unroll
    for (int j = 0; j < 10; ++j) ge[j] = (iv[j] >= v);
#pragma unroll
    for (int j = 9; j >= 1; --j)
        iv[j] = ge[j] ? iv[j] : (ge[j - 1] ? v : iv[j - 1]);
    if (!ge[0]) iv[0] = v;
}

__device__ __forceinline__ void bitonic16_u64(unsigned long long (&v)[16]) {
#pragma unroll
    for (int d = 8; d >= 1; d >>= 1) {
#pragma unroll
        for (int i = 0; i < 16; ++i) {
            if ((i & d) == 0) {
                if (v[i | d] < v[i]) {
                    unsigned long long t = v[i]; v[i] = v[i | d]; v[i | d] = t;
                }
            }
        }
    }
}

__device__ __forceinline__ void bitonic16_desc(float (&v)[16]) {
#pragma unroll
    for (int d = 8; d >= 1; d >>= 1) {
#pragma unroll
        for (int i = 0; i < 16; ++i) {
            if ((i & d) == 0) {
                if (v[i | d] > v[i]) { float t = v[i]; v[i] = v[i | d]; v[i | d] = t; }
            }
        }
    }
}

template <bool USE_F>
__global__ __launch_bounds__(128, 4) void kF(
    const float* __restrict__ boxes,    // [BS][Qn][4]
    const int*   __restrict__ labels,   // [BS][Gn]
    const float* __restrict__ tboxes,   // [BS][Gn][4]
    const float* __restrict__ logits,   // [BS][Qn][Cn] (fallback gather)
    const float* __restrict__ F,        // [BS][Cn][Qn] in d_ws (primary)
    float* __restrict__ out,            // cost -> [b][0]
    float* __restrict__ thrv,           // [BS*Gn]
    int*   __restrict__ thri)           // [BS*Gn]
{
    const int lane = threadIdx.x & 63;
    const int wid  = threadIdx.x >> 6;
    const int r    = blockIdx.x;
    const int b    = r >> 7;
    const int g    = r & (Gn - 1);
    const int lab  = labels[r];

    const float* tb = tboxes + (size_t)r * 4;
    const float tcx = tb[0], tcy = tb[1], tw = tb[2], th = tb[3];
    const float tx0 = tcx - 0.5f * tw, ty0 = tcy - 0.5f * th;
    const float tx1 = tcx + 0.5f * tw, ty1 = tcy + 0.5f * th;
    const float tarea = (tx1 - tx0) * (ty1 - ty0);

    const float*  Frow = USE_F ? (F + ((size_t)b * Cn + lab) * Qn) : nullptr;
    const float*  lcol = USE_F ? nullptr : (logits + (size_t)b * Qn * Cn + lab);
    float*        crow = out + (size_t)(b * 2) * Gn * Qn + (size_t)g * Qn;
    const float4* brow = reinterpret_cast<const float4*>(boxes) + (size_t)b * Qn;

    unsigned long long kv[10];
    float iv[10];
#pragma unroll
    for (int j = 0; j < 10; ++j) { kv[j] = ~0ull; iv[j] = -INFINITY; }

#pragma unroll
    for (int it = 0; it < 8; ++it) {
        const int q0 = it * 512 + wid * 256 + lane * 4;
        if (q0 < Qn) {
            float cls4[4];
            if (USE_F) {
                const float4 f4 = *reinterpret_cast<const float4*>(Frow + q0);
                cls4[0] = f4.x; cls4[1] = f4.y; cls4[2] = f4.z; cls4[3] = f4.w;
            } else {
#pragma unroll
                for (int e = 0; e < 4; ++e)
                    cls4[e] = focal_cost(lcol[(size_t)(q0 + e) * Cn]);
            }
            float c4[4];
#pragma unroll
            for (int e = 0; e < 4; ++e) {
                const float cls = cls4[e];
                const float4 bb = brow[q0 + e];
                const float cx = bb.x, cy = bb.y, w = bb.z, h = bb.w;
                const float x0 = cx - 0.5f * w, y0 = cy - 0.5f * h;
                const float x1 = cx + 0.5f * w, y1 = cy + 0.5f * h;
                const float area1 = (x1 - x0) * (y1 - y0);
                const float l1 = ((fabsf(cx - tcx) + fabsf(cy - tcy))
                                  + fabsf(w - tw)) + fabsf(h - th);
                const float ltx = fmaxf(x0, tx0), lty = fmaxf(y0, ty0);
                const float rbx = fminf(x1, tx1), rby = fminf(y1, ty1);
                const float iw = fmaxf(rbx - ltx, 0.0f), ih = fmaxf(rby - lty, 0.0f);
                const float inter = iw * ih;
                const float uni = (area1 + tarea) - inter;
                const float iou = inter / (uni + kEPS);
                const float cltx = fminf(x0, tx0), clty = fminf(y0, ty0);
                const float crbx = fmaxf(x1, tx1), crby = fmaxf(y1, ty1);
                const float cw = fmaxf(crbx - cltx, 0.0f), ch = fmaxf(crby - clty, 0.0f);
                const float areac = cw * ch;
                const float giou = iou - (areac - uni) / (areac + kEPS);

                const float cost = (5.0f * l1 + 2.0f * cls) + 2.0f * (-giou);
                c4[e] = cost;
                ins10_u64(kv, pack_ci(cost, q0 + e));
                ins10_desc(iv, iou);
            }
            float4 cv4; cv4.x = c4[0]; cv4.y = c4[1]; cv4.z = c4[2]; cv4.w = c4[3];
            *reinterpret_cast<float4*>(crow + q0) = cv4;
        }
    }

    // pad to 16 for the proven merge networks
    unsigned long long cm16[16];
    float im16[16];
#pragma unroll
    for (int j = 0; j < 16; ++j) {
        cm16[j] = (j < 10) ? kv[j] : ~0ull;
        im16[j] = (j < 10) ? iv[j] : -INFINITY;
    }

    // wave-internal butterfly; register-lean two-half form (save 8, not 16)
#pragma unroll
    for (int m = 1; m <= 32; m <<= 1) {
        unsigned long long s8[8];
#pragma unroll
        for (int j = 0; j < 8; ++j) s8[j] = cm16[j];
#pragma unroll
        for (int j = 0; j < 8; ++j) {           // reads cm16[8..15] (unmodified)
            const unsigned long long t = shfl_xor_u64(cm16[15 - j], m);
            if (t < cm16[j]) cm16[j] = t;
        }
#pragma unroll
        for (int j = 8; j < 16; ++j) {          // reads partner's saved originals
            const unsigned long long t = shfl_xor_u64(s8[15 - j], m);
            if (t < cm16[j]) cm16[j] = t;
        }
        bitonic16_u64(cm16);

        float f8[8];
#pragma unroll
        for (int j = 0; j < 8; ++j) f8[j] = im16[j];
#pragma unroll
        for (int j = 0; j < 8; ++j)
            im16[j] = fmaxf(im16[j], __shfl_xor(im16[15 - j], m, 64));
#pragma unroll
        for (int j = 8; j < 16; ++j)
            im16[j] = fmaxf(im16[j], __shfl_xor(f8[15 - j], m, 64));
        bitonic16_desc(im16);
    }

    __shared__ unsigned long long s_c16[16];
    __shared__ float s_i16[16];
    if (wid == 1 && lane == 0) {
#pragma unroll
        for (int j = 0; j < 16; ++j) { s_c16[j] = cm16[j]; s_i16[j] = im16[j]; }
    }
    __syncthreads();

    if (wid == 0 && lane == 0) {
#pragma unroll
        for (int j = 0; j < 16; ++j) {
            const unsigned long long t = s_c16[15 - j];
            if (t < cm16[j]) cm16[j] = t;
            im16[j] = fmaxf(im16[j], s_i16[15 - j]);
        }
        bitonic16_u64(cm16);
        bitonic16_desc(im16);

        float s = 0.0f;
#pragma unroll
        for (int j = 0; j < 10; ++j) s += im16[j];  // descending, like top_k+sum
        int k = (int)s;                              // trunc (s >= 0)
        if (k < 1) k = 1;
        if (k > 10) k = 10;

        unsigned long long key = cm16[0];
#pragma unroll
        for (int j = 1; j < 10; ++j) key = (k == j + 1) ? cm16[j] : key;
        const unsigned int su = (unsigned int)(key >> 32);
        thrv[r] = __uint_as_float((su & 0x80000000u) ? (su ^ 0x80000000u) : ~su);
        thri[r] = (int)(unsigned int)key;
    }
}

// ---------------------------------------------------------------------------
// kC: per anchor column q: matching + (>1 matched) argmin fixup.
// Sole writer of out[b][1].
// ---------------------------------------------------------------------------
__global__ __launch_bounds__(256) void kC_match(
    const float* __restrict__ outc,     // cost at [b][0][g][q]
    const float* __restrict__ thrv,
    const int*   __restrict__ thri,
    float* __restrict__ out)            // matching at [b][1][g][q]
{
    const int b = blockIdx.y;
    const int q = blockIdx.x * 256 + threadIdx.x;

    __shared__ float s_tv[Gn];
    __shared__ int   s_ti[Gn];
    if (threadIdx.x < Gn) {
        s_tv[threadIdx.x] = thrv[b * Gn + threadIdx.x];
        s_ti[threadIdx.x] = thri[b * Gn + threadIdx.x];
    }
    __syncthreads();
    if (q >= Qn) return;

    const float* crow = outc + (size_t)(b * 2) * Gn * Qn + q;
    unsigned long long m0 = 0, m1 = 0;
    float minc = INFINITY;
    int ming = 0;
    for (int g = 0; g < Gn; ++g) {
        const float c = crow[(size_t)g * Qn];
        const bool mt = (c < s_tv[g]) || (c == s_tv[g] && q <= s_ti[g]);
        if (g < 64) m0 |= (unsigned long long)mt << g;
        else        m1 |= (unsigned long long)mt << (g - 64);
        if (c < minc) { minc = c; ming = g; }   // strict: first argmin
    }
    const int cnt = __popcll(m0) + __popcll(m1);
    const bool fix = (cnt > 1);

    float* mrow = out + (size_t)(b * 2 + 1) * Gn * Qn + q;
    for (int g = 0; g < Gn; ++g) {
        const bool bit = (g < 64) ? ((m0 >> g) & 1ull) : ((m1 >> (g - 64)) & 1ull);
        const bool mt = fix ? (g == ming) : bit;
        mrow[(size_t)g * Qn] = mt ? 1.0f : 0.0f;
    }
}

// ---------------------------------------------------------------------------
extern "C" void kernel_launch(void* const* d_in, const int* in_sizes, int n_in,
                              void* d_out, int out_size, void* d_ws, size_t ws_size,
                              hipStream_t stream) {
    (void)in_sizes; (void)n_in; (void)out_size;
    const float* logits = (const float*)d_in[0];
    const float* boxes  = (const float*)d_in[1];
    const int*   labels = (const int*)d_in[2];
    const float* tboxes = (const float*)d_in[3];
    float* out = (float*)d_out;

    float* thrv = (float*)((char*)d_ws + kThrvOff);   // [BS*Gn]
    int*   thri = (int*)  ((char*)d_ws + kThriOff);   // [BS*Gn]
    float* F    = (float*)((char*)d_ws + kFOff);      // [BS][Cn][Qn]

    const bool use_f = (ws_size >= kFOff + kFBytes);

    dim3 gF(BS * Gn);                     // one row per block, 2 waves
    if (use_f) {
        dim3 gP(Qn / 32, BS);             // 125 x 16
        kP_focal<<<gP, 256, 0, stream>>>(logits, F);
        kF<true><<<gF, 128, 0, stream>>>(boxes, labels, tboxes, logits, F,
                                         out, thrv, thri);
    } else {
        kF<false><<<gF, 128, 0, stream>>>(boxes, labels, tboxes, logits, nullptr,
                                          out, thrv, thri);
    }

    dim3 gC((Qn + 255) / 256, BS);
    kC_match<<<gC, 256, 0, stream>>>(out, thrv, thri, out);
}

// Round 7
// 132.344 us; speedup vs baseline: 2.4660x; 1.0700x over previous
//
#include <hip/hip_runtime.h>
#include <cmath>
#include <cfloat>
#include <climits>

// Match numpy's un-fused f32 arithmetic: matching output is binary, so order
// decisions at the k-th-smallest boundary must agree with the reference.
#pragma clang fp contract(off)

static constexpr int BS = 16;
static constexpr int Qn = 4000;
static constexpr int Cn = 80;
static constexpr int Gn = 128;
static constexpr float kEPS = 1e-8f;

// Replay-invariance rule (learned round 5): every byte of d_out/d_ws holds
// exactly ONE value per call, identical across calls.
//
// d_ws layout: [0,8K) thrv | [8K,16K) thri | [16K, 16K+20.48M) F[b][c][q]

static constexpr size_t kThrvOff = 0;
static constexpr size_t kThriOff = 8 * 1024;
static constexpr size_t kFOff    = 16 * 1024;
static constexpr size_t kFBytes  = (size_t)BS * Cn * Qn * sizeof(float);

__device__ __forceinline__ float focal_cost(float l) {
    const float p = 1.0f / (1.0f + expf(-l));
    const float neg = (0.75f * (p * p)) * (-log1pf(-p + kEPS));
    const float pos = (0.25f * ((1.0f - p) * (1.0f - p))) * (-logf(p + kEPS));
    return pos - neg;
}

// ---------------------------------------------------------------------------
// kP: focal class cost, transposed into d_ws: F[b][c][q].
// ---------------------------------------------------------------------------
__global__ __launch_bounds__(256) void kP_focal(
    const float* __restrict__ logits,   // [BS][Qn][Cn]
    float* __restrict__ F)              // [BS][Cn][Qn]
{
    const int b  = blockIdx.y;
    const int q0 = blockIdx.x * 32;
    const int t  = threadIdx.x;

    __shared__ float s_f[32 * 81];      // [ql][c] padded

    const float* src = logits + ((size_t)b * Qn + q0) * Cn;
#pragma unroll
    for (int i = 0; i < 10; ++i) {
        const int idx = t + i * 256;    // < 2560 = 32*80
        const int ql = idx / 80, c = idx % 80;
        s_f[ql * 81 + c] = focal_cost(src[idx]);
    }
    __syncthreads();

    float* dst = F + (size_t)b * Cn * Qn;
#pragma unroll
    for (int i = 0; i < 10; ++i) {
        const int j = t + i * 256;
        const int c = j >> 5, ql = j & 31;
        dst[(size_t)c * Qn + q0 + ql] = s_f[ql * 81 + c];
    }
}

// ---------------------------------------------------------------------------
// kF v2: fused cost + selection, 4 waves per (b,g) row (16 elems/lane).
// Streams q: class cost + boxes -> L1/IoU/GIoU -> cost (written once) and
// in-register top-10 lists (u64-packed cost, f32 iou). Shuffle butterfly
// per wave, then 3-partner LDS merge on wave 0.
// ---------------------------------------------------------------------------
__device__ __forceinline__ unsigned long long pack_ci(float c, int q) {
    const unsigned int u = __float_as_uint(c + 0.0f);       // -0.0 -> +0.0
    const unsigned int s = (u & 0x80000000u) ? ~u : (u | 0x80000000u);
    return ((unsigned long long)s << 32) | (unsigned int)q;
}

__device__ __forceinline__ unsigned long long shfl_xor_u64(unsigned long long v, int m) {
    const int lo = __shfl_xor((int)(unsigned int)v, m, 64);
    const int hi = __shfl_xor((int)(unsigned int)(v >> 32), m, 64);
    return ((unsigned long long)(unsigned int)hi << 32) | (unsigned int)lo;
}

__device__ __forceinline__ void ins10_u64(unsigned long long (&kv)[10], unsigned long long nk) {
    bool le[10];
#pragma unroll
    for (int j = 0; j < 10; ++j) le[j] = (kv[j] < nk);
#pragma unroll
    for (int j = 9; j >= 1; --j)
        kv[j] = le[j] ? kv[j] : (le[j - 1] ? nk : kv[j - 1]);
    if (!le[0]) kv[0] = nk;
}

__device__ __forceinline__ void ins10_desc(float (&iv)[10], float v) {
    bool ge[10];
#pragma unroll
    for (int j = 0; j < 10; ++j) ge[j] = (iv[j] >= v);
#pragma unroll
    for (int j = 9; j >= 1; --j)
        iv[j] = ge[j] ? iv[j] : (ge[j - 1] ? v : iv[j - 1]);
    if (!ge[0]) iv[0] = v;
}

__device__ __forceinline__ void bitonic16_u64(unsigned long long (&v)[16]) {
#pragma unroll
    for (int d = 8; d >= 1; d >>= 1) {
#pragma unroll
        for (int i = 0; i < 16; ++i) {
            if ((i & d) == 0) {
                if (v[i | d] < v[i]) {
                    unsigned long long t = v[i]; v[i] = v[i | d]; v[i | d] = t;
                }
            }
        }
    }
}

__device__ __forceinline__ void bitonic16_desc(float (&v)[16]) {
#pragma unroll
    for (int d = 8; d >= 1; d >>= 1) {
#pragma unroll
        for (int i = 0; i < 16; ++i) {
            if ((i & d) == 0) {
                if (v[i | d] > v[i]) { float t = v[i]; v[i] = v[i | d]; v[i | d] = t; }
            }
        }
    }
}

template <bool USE_F>
__global__ __launch_bounds__(256) void kF(
    const float* __restrict__ boxes,    // [BS][Qn][4]
    const int*   __restrict__ labels,   // [BS][Gn]
    const float* __restrict__ tboxes,   // [BS][Gn][4]
    const float* __restrict__ logits,   // [BS][Qn][Cn] (fallback gather)
    const float* __restrict__ F,        // [BS][Cn][Qn] in d_ws (primary)
    float* __restrict__ out,            // cost -> [b][0]
    float* __restrict__ thrv,           // [BS*Gn]
    int*   __restrict__ thri)           // [BS*Gn]
{
    const int lane = threadIdx.x & 63;
    const int wid  = threadIdx.x >> 6;  // 0..3
    const int r    = blockIdx.x;
    const int b    = r >> 7;
    const int g    = r & (Gn - 1);
    const int lab  = labels[r];

    const float* tb = tboxes + (size_t)r * 4;
    const float tcx = tb[0], tcy = tb[1], tw = tb[2], th = tb[3];
    const float tx0 = tcx - 0.5f * tw, ty0 = tcy - 0.5f * th;
    const float tx1 = tcx + 0.5f * tw, ty1 = tcy + 0.5f * th;
    const float tarea = (tx1 - tx0) * (ty1 - ty0);

    const float*  Frow = USE_F ? (F + ((size_t)b * Cn + lab) * Qn) : nullptr;
    const float*  lcol = USE_F ? nullptr : (logits + (size_t)b * Qn * Cn + lab);
    float*        crow = out + (size_t)(b * 2) * Gn * Qn + (size_t)g * Qn;
    const float4* brow = reinterpret_cast<const float4*>(boxes) + (size_t)b * Qn;

    unsigned long long kv[10];
    float iv[10];
#pragma unroll
    for (int j = 0; j < 10; ++j) { kv[j] = ~0ull; iv[j] = -INFINITY; }

#pragma unroll
    for (int it = 0; it < 4; ++it) {
        const int q0 = it * 1024 + wid * 256 + lane * 4;
        if (q0 < Qn) {
            float cls4[4];
            if (USE_F) {
                const float4 f4 = *reinterpret_cast<const float4*>(Frow + q0);
                cls4[0] = f4.x; cls4[1] = f4.y; cls4[2] = f4.z; cls4[3] = f4.w;
            } else {
#pragma unroll
                for (int e = 0; e < 4; ++e)
                    cls4[e] = focal_cost(lcol[(size_t)(q0 + e) * Cn]);
            }
            float c4[4];
#pragma unroll
            for (int e = 0; e < 4; ++e) {
                const float cls = cls4[e];
                const float4 bb = brow[q0 + e];
                const float cx = bb.x, cy = bb.y, w = bb.z, h = bb.w;
                const float x0 = cx - 0.5f * w, y0 = cy - 0.5f * h;
                const float x1 = cx + 0.5f * w, y1 = cy + 0.5f * h;
                const float area1 = (x1 - x0) * (y1 - y0);
                const float l1 = ((fabsf(cx - tcx) + fabsf(cy - tcy))
                                  + fabsf(w - tw)) + fabsf(h - th);
                const float ltx = fmaxf(x0, tx0), lty = fmaxf(y0, ty0);
                const float rbx = fminf(x1, tx1), rby = fminf(y1, ty1);
                const float iw = fmaxf(rbx - ltx, 0.0f), ih = fmaxf(rby - lty, 0.0f);
                const float inter = iw * ih;
                const float uni = (area1 + tarea) - inter;
                const float iou = inter / (uni + kEPS);
                const float cltx = fminf(x0, tx0), clty = fminf(y0, ty0);
                const float crbx = fmaxf(x1, tx1), crby = fmaxf(y1, ty1);
                const float cw = fmaxf(crbx - cltx, 0.0f), ch = fmaxf(crby - clty, 0.0f);
                const float areac = cw * ch;
                const float giou = iou - (areac - uni) / (areac + kEPS);

                const float cost = (5.0f * l1 + 2.0f * cls) + 2.0f * (-giou);
                c4[e] = cost;
                ins10_u64(kv, pack_ci(cost, q0 + e));
                ins10_desc(iv, iou);
            }
            float4 cv4; cv4.x = c4[0]; cv4.y = c4[1]; cv4.z = c4[2]; cv4.w = c4[3];
            *reinterpret_cast<float4*>(crow + q0) = cv4;
        }
    }

    // pad to 16 for the proven merge networks
    unsigned long long cm16[16];
    float im16[16];
#pragma unroll
    for (int j = 0; j < 16; ++j) {
        cm16[j] = (j < 10) ? kv[j] : ~0ull;
        im16[j] = (j < 10) ? iv[j] : -INFINITY;
    }

    // wave-internal butterfly; register-lean two-half form (save 8, not 16)
#pragma unroll
    for (int m = 1; m <= 32; m <<= 1) {
        unsigned long long s8[8];
#pragma unroll
        for (int j = 0; j < 8; ++j) s8[j] = cm16[j];
#pragma unroll
        for (int j = 0; j < 8; ++j) {           // reads cm16[8..15] (unmodified)
            const unsigned long long t = shfl_xor_u64(cm16[15 - j], m);
            if (t < cm16[j]) cm16[j] = t;
        }
#pragma unroll
        for (int j = 8; j < 16; ++j) {          // reads partner's saved originals
            const unsigned long long t = shfl_xor_u64(s8[15 - j], m);
            if (t < cm16[j]) cm16[j] = t;
        }
        bitonic16_u64(cm16);

        float f8[8];
#pragma unroll
        for (int j = 0; j < 8; ++j) f8[j] = im16[j];
#pragma unroll
        for (int j = 0; j < 8; ++j)
            im16[j] = fmaxf(im16[j], __shfl_xor(im16[15 - j], m, 64));
#pragma unroll
        for (int j = 8; j < 16; ++j)
            im16[j] = fmaxf(im16[j], __shfl_xor(f8[15 - j], m, 64));
        bitonic16_desc(im16);
    }

    // cross-wave: waves 1..3 publish, wave 0 lane 0 merges all three.
    __shared__ unsigned long long s_c16[3][16];
    __shared__ float s_i16[3][16];
    if (wid > 0 && lane == 0) {
#pragma unroll
        for (int j = 0; j < 16; ++j) {
            s_c16[wid - 1][j] = cm16[j];
            s_i16[wid - 1][j] = im16[j];
        }
    }
    __syncthreads();

    if (wid == 0 && lane == 0) {
#pragma unroll
        for (int p = 0; p < 3; ++p) {
#pragma unroll
            for (int j = 0; j < 16; ++j) {
                const unsigned long long t = s_c16[p][15 - j];
                if (t < cm16[j]) cm16[j] = t;
                im16[j] = fmaxf(im16[j], s_i16[p][15 - j]);
            }
            bitonic16_u64(cm16);
            bitonic16_desc(im16);
        }

        float s = 0.0f;
#pragma unroll
        for (int j = 0; j < 10; ++j) s += im16[j];  // descending, like top_k+sum
        int k = (int)s;                              // trunc (s >= 0)
        if (k < 1) k = 1;
        if (k > 10) k = 10;

        unsigned long long key = cm16[0];
#pragma unroll
        for (int j = 1; j < 10; ++j) key = (k == j + 1) ? cm16[j] : key;
        const unsigned int su = (unsigned int)(key >> 32);
        thrv[r] = __uint_as_float((su & 0x80000000u) ? (su ^ 0x80000000u) : ~su);
        thri[r] = (int)(unsigned int)key;
    }
}

// ---------------------------------------------------------------------------
// kC v2: matching + (>1 matched) argmin fixup, g-split across 4 waves.
// Block: 4 waves over a 64-q tile; wave w owns g in [32w, 32w+32).
// Sole writer of out[b][1].
// ---------------------------------------------------------------------------
__global__ __launch_bounds__(256) void kC2(
    const float* __restrict__ outc,     // cost at [b][0][g][q]
    const float* __restrict__ thrv,
    const int*   __restrict__ thri,
    float* __restrict__ out)            // matching at [b][1][g][q]
{
    const int b  = blockIdx.y;
    const int lq = threadIdx.x & 63;
    const int gh = threadIdx.x >> 6;    // 0..3
    const int q  = blockIdx.x * 64 + lq;

    __shared__ float    s_tv[Gn];
    __shared__ int      s_ti[Gn];
    __shared__ unsigned s_mask[4][64];
    __shared__ float    s_mv[4][64];
    __shared__ int      s_mg[4][64];

    if (threadIdx.x < Gn) {
        s_tv[threadIdx.x] = thrv[b * Gn + threadIdx.x];
        s_ti[threadIdx.x] = thri[b * Gn + threadIdx.x];
    }
    __syncthreads();

    const float* crow = outc + (size_t)(b * 2) * Gn * Qn + q;
    unsigned mask = 0;
    float mv = INFINITY;
    int mg = 0;
    const int gbase = gh * 32;
    if (q < Qn) {
#pragma unroll
        for (int j = 0; j < 32; ++j) {
            const int g = gbase + j;
            const float c = crow[(size_t)g * Qn];
            const bool mt = (c < s_tv[g]) || (c == s_tv[g] && q <= s_ti[g]);
            mask |= (unsigned)mt << j;
            if (c < mv) { mv = c; mg = g; }   // strict: first argmin in chunk
        }
    }
    s_mask[gh][lq] = mask;
    s_mv[gh][lq]   = mv;
    s_mg[gh][lq]   = mg;
    __syncthreads();

    // full-column combine (each thread independently; LDS broadcast-friendly)
    const int cnt = __popc(s_mask[0][lq]) + __popc(s_mask[1][lq])
                  + __popc(s_mask[2][lq]) + __popc(s_mask[3][lq]);
    float bmv = s_mv[0][lq];
    int   bmg = s_mg[0][lq];
#pragma unroll
    for (int h = 1; h < 4; ++h) {
        const float v = s_mv[h][lq];
        if (v < bmv) { bmv = v; bmg = s_mg[h][lq]; }  // ascending h: first argmin
    }
    const bool fix = (cnt > 1);

    if (q < Qn) {
        float* mrow = out + (size_t)(b * 2 + 1) * Gn * Qn + q;
#pragma unroll
        for (int j = 0; j < 32; ++j) {
            const int g = gbase + j;
            const bool bit = (mask >> j) & 1u;
            const bool mt = fix ? (g == bmg) : bit;
            mrow[(size_t)g * Qn] = mt ? 1.0f : 0.0f;
        }
    }
}

// ---------------------------------------------------------------------------
extern "C" void kernel_launch(void* const* d_in, const int* in_sizes, int n_in,
                              void* d_out, int out_size, void* d_ws, size_t ws_size,
                              hipStream_t stream) {
    (void)in_sizes; (void)n_in; (void)out_size;
    const float* logits = (const float*)d_in[0];
    const float* boxes  = (const float*)d_in[1];
    const int*   labels = (const int*)d_in[2];
    const float* tboxes = (const float*)d_in[3];
    float* out = (float*)d_out;

    float* thrv = (float*)((char*)d_ws + kThrvOff);   // [BS*Gn]
    int*   thri = (int*)  ((char*)d_ws + kThriOff);   // [BS*Gn]
    float* F    = (float*)((char*)d_ws + kFOff);      // [BS][Cn][Qn]

    const bool use_f = (ws_size >= kFOff + kFBytes);

    dim3 gF(BS * Gn);                     // one row per block, 4 waves
    if (use_f) {
        dim3 gP(Qn / 32, BS);             // 125 x 16
        kP_focal<<<gP, 256, 0, stream>>>(logits, F);
        kF<true><<<gF, 256, 0, stream>>>(boxes, labels, tboxes, logits, F,
                                         out, thrv, thri);
    } else {
        kF<false><<<gF, 256, 0, stream>>>(boxes, labels, tboxes, logits, nullptr,
                                          out, thrv, thri);
    }

    dim3 gC((Qn + 63) / 64, BS);          // 63 x 16, 4 waves each
    kC2<<<gC, 256, 0, stream>>>(out, thrv, thri, out);
}

// Round 8
// 111.017 us; speedup vs baseline: 2.9397x; 1.1921x over previous
//
#include <hip/hip_runtime.h>
#include <cmath>
#include <cfloat>
#include <climits>

// Match numpy's un-fused f32 arithmetic: matching output is binary, so order
// decisions at the k-th-smallest boundary must agree with the reference.
#pragma clang fp contract(off)

static constexpr int BS = 16;
static constexpr int Qn = 4000;
static constexpr int Cn = 80;
static constexpr int Gn = 128;
static constexpr float kEPS = 1e-8f;

// Replay-invariance rule (learned round 5): every byte of d_out/d_ws holds
// exactly ONE value per call, identical across calls.
//
// d_ws layout: [0,8K) thrv | [8K,16K) thri | [16K, 16K+20.48M) F[b][c][q]

static constexpr size_t kThrvOff = 0;
static constexpr size_t kThriOff = 8 * 1024;
static constexpr size_t kFOff    = 16 * 1024;
static constexpr size_t kFBytes  = (size_t)BS * Cn * Qn * sizeof(float);

__device__ __forceinline__ float focal_cost(float l) {
    const float p = 1.0f / (1.0f + expf(-l));
    const float neg = (0.75f * (p * p)) * (-log1pf(-p + kEPS));
    const float pos = (0.25f * ((1.0f - p) * (1.0f - p))) * (-logf(p + kEPS));
    return pos - neg;
}

// ---------------------------------------------------------------------------
// kP: focal class cost, transposed into d_ws: F[b][c][q].
// ---------------------------------------------------------------------------
__global__ __launch_bounds__(256) void kP_focal(
    const float* __restrict__ logits,   // [BS][Qn][Cn]
    float* __restrict__ F)              // [BS][Cn][Qn]
{
    const int b  = blockIdx.y;
    const int q0 = blockIdx.x * 32;
    const int t  = threadIdx.x;

    __shared__ float s_f[32 * 81];      // [ql][c] padded

    const float* src = logits + ((size_t)b * Qn + q0) * Cn;
#pragma unroll
    for (int i = 0; i < 10; ++i) {
        const int idx = t + i * 256;    // < 2560 = 32*80
        const int ql = idx / 80, c = idx % 80;
        s_f[ql * 81 + c] = focal_cost(src[idx]);
    }
    __syncthreads();

    float* dst = F + (size_t)b * Cn * Qn;
#pragma unroll
    for (int i = 0; i < 10; ++i) {
        const int j = t + i * 256;
        const int c = j >> 5, ql = j & 31;
        dst[(size_t)c * Qn + q0 + ql] = s_f[ql * 81 + c];
    }
}

// ---------------------------------------------------------------------------
// kF v3: fused cost + selection, 2 waves per (b,g) row (32 elems/lane).
// Streams q -> cost (written once) + in-register top-10 lists. Merge via
// 10x wave min/max EXTRACTION (shfl_xor reduce + predicated head pop),
// then a tiny serial two-pointer merge across the 2 waves on thread 0.
// ---------------------------------------------------------------------------
__device__ __forceinline__ unsigned long long pack_ci(float c, int q) {
    const unsigned int u = __float_as_uint(c + 0.0f);       // -0.0 -> +0.0
    const unsigned int s = (u & 0x80000000u) ? ~u : (u | 0x80000000u);
    return ((unsigned long long)s << 32) | (unsigned int)q;
}

__device__ __forceinline__ unsigned long long shfl_xor_u64(unsigned long long v, int m) {
    const int lo = __shfl_xor((int)(unsigned int)v, m, 64);
    const int hi = __shfl_xor((int)(unsigned int)(v >> 32), m, 64);
    return ((unsigned long long)(unsigned int)hi << 32) | (unsigned int)lo;
}

__device__ __forceinline__ void ins10_u64(unsigned long long (&kv)[10], unsigned long long nk) {
    bool le[10];
#pragma unroll
    for (int j = 0; j < 10; ++j) le[j] = (kv[j] < nk);
#pragma unroll
    for (int j = 9; j >= 1; --j)
        kv[j] = le[j] ? kv[j] : (le[j - 1] ? nk : kv[j - 1]);
    if (!le[0]) kv[0] = nk;
}

__device__ __forceinline__ void ins10_desc(float (&iv)[10], float v) {
    bool ge[10];
#pragma unroll
    for (int j = 0; j < 10; ++j) ge[j] = (iv[j] >= v);
#pragma unroll
    for (int j = 9; j >= 1; --j)
        iv[j] = ge[j] ? iv[j] : (ge[j - 1] ? v : iv[j - 1]);
    if (!ge[0]) iv[0] = v;
}

template <bool USE_F>
__global__ __launch_bounds__(128, 4) void kF(
    const float* __restrict__ boxes,    // [BS][Qn][4]
    const int*   __restrict__ labels,   // [BS][Gn]
    const float* __restrict__ tboxes,   // [BS][Gn][4]
    const float* __restrict__ logits,   // [BS][Qn][Cn] (fallback gather)
    const float* __restrict__ F,        // [BS][Cn][Qn] in d_ws (primary)
    float* __restrict__ out,            // cost -> [b][0]
    float* __restrict__ thrv,           // [BS*Gn]
    int*   __restrict__ thri)           // [BS*Gn]
{
    const int lane = threadIdx.x & 63;
    const int wid  = threadIdx.x >> 6;  // 0..1
    const int r    = blockIdx.x;
    const int b    = r >> 7;
    const int g    = r & (Gn - 1);
    const int lab  = labels[r];

    const float* tb = tboxes + (size_t)r * 4;
    const float tcx = tb[0], tcy = tb[1], tw = tb[2], th = tb[3];
    const float tx0 = tcx - 0.5f * tw, ty0 = tcy - 0.5f * th;
    const float tx1 = tcx + 0.5f * tw, ty1 = tcy + 0.5f * th;
    const float tarea = (tx1 - tx0) * (ty1 - ty0);

    const float*  Frow = USE_F ? (F + ((size_t)b * Cn + lab) * Qn) : nullptr;
    const float*  lcol = USE_F ? nullptr : (logits + (size_t)b * Qn * Cn + lab);
    float*        crow = out + (size_t)(b * 2) * Gn * Qn + (size_t)g * Qn;
    const float4* brow = reinterpret_cast<const float4*>(boxes) + (size_t)b * Qn;

    unsigned long long kv[10];
    float iv[10];
#pragma unroll
    for (int j = 0; j < 10; ++j) { kv[j] = ~0ull; iv[j] = -INFINITY; }

#pragma unroll
    for (int it = 0; it < 8; ++it) {
        const int q0 = it * 512 + wid * 256 + lane * 4;
        if (q0 < Qn) {
            float cls4[4];
            if (USE_F) {
                const float4 f4 = *reinterpret_cast<const float4*>(Frow + q0);
                cls4[0] = f4.x; cls4[1] = f4.y; cls4[2] = f4.z; cls4[3] = f4.w;
            } else {
#pragma unroll
                for (int e = 0; e < 4; ++e)
                    cls4[e] = focal_cost(lcol[(size_t)(q0 + e) * Cn]);
            }
            float c4[4];
#pragma unroll
            for (int e = 0; e < 4; ++e) {
                const float cls = cls4[e];
                const float4 bb = brow[q0 + e];
                const float cx = bb.x, cy = bb.y, w = bb.z, h = bb.w;
                const float x0 = cx - 0.5f * w, y0 = cy - 0.5f * h;
                const float x1 = cx + 0.5f * w, y1 = cy + 0.5f * h;
                const float area1 = (x1 - x0) * (y1 - y0);
                const float l1 = ((fabsf(cx - tcx) + fabsf(cy - tcy))
                                  + fabsf(w - tw)) + fabsf(h - th);
                const float ltx = fmaxf(x0, tx0), lty = fmaxf(y0, ty0);
                const float rbx = fminf(x1, tx1), rby = fminf(y1, ty1);
                const float iw = fmaxf(rbx - ltx, 0.0f), ih = fmaxf(rby - lty, 0.0f);
                const float inter = iw * ih;
                const float uni = (area1 + tarea) - inter;
                const float iou = inter / (uni + kEPS);
                const float cltx = fminf(x0, tx0), clty = fminf(y0, ty0);
                const float crbx = fmaxf(x1, tx1), crby = fmaxf(y1, ty1);
                const float cw = fmaxf(crbx - cltx, 0.0f), ch = fmaxf(crby - clty, 0.0f);
                const float areac = cw * ch;
                const float giou = iou - (areac - uni) / (areac + kEPS);

                const float cost = (5.0f * l1 + 2.0f * cls) + 2.0f * (-giou);
                c4[e] = cost;
                ins10_u64(kv, pack_ci(cost, q0 + e));
                ins10_desc(iv, iou);
            }
            float4 cv4; cv4.x = c4[0]; cv4.y = c4[1]; cv4.z = c4[2]; cv4.w = c4[3];
            *reinterpret_cast<float4*>(crow + q0) = cv4;
        }
    }

    // ---- wave-level extraction: 10 smallest cost keys (unique u64) ----
    unsigned long long e[10];
#pragma unroll
    for (int t = 0; t < 10; ++t) {
        unsigned long long m = kv[0];
#pragma unroll
        for (int d = 1; d <= 32; d <<= 1) {
            const unsigned long long o = shfl_xor_u64(m, d);
            if (o < m) m = o;
        }
        e[t] = m;                       // all lanes agree
        if (kv[0] == m) {               // unique keys -> exactly one owner
#pragma unroll
            for (int j = 0; j < 9; ++j) kv[j] = kv[j + 1];
            kv[9] = ~0ull;
        }
    }

    // ---- wave-level extraction: 10 largest ious (ties: pop first owner) ----
    float f[10];
#pragma unroll
    for (int t = 0; t < 10; ++t) {
        float m = iv[0];
#pragma unroll
        for (int d = 1; d <= 32; d <<= 1)
            m = fmaxf(m, __shfl_xor(m, d, 64));
        f[t] = m;
        const bool own0 = (iv[0] == m);
        const unsigned long long bal = __ballot(own0);
        if (own0 && lane == __ffsll((long long)bal) - 1) {
#pragma unroll
            for (int j = 0; j < 9; ++j) iv[j] = iv[j + 1];
            iv[9] = -INFINITY;
        }
    }

    // ---- cross-wave: both waves publish sorted-10s; thread 0 merges ----
    __shared__ unsigned long long s_e[2][12];
    __shared__ float s_f[2][12];
    if (lane == 0) {
#pragma unroll
        for (int j = 0; j < 10; ++j) { s_e[wid][j] = e[j]; s_f[wid][j] = f[j]; }
        s_e[wid][10] = ~0ull;      s_e[wid][11] = ~0ull;
        s_f[wid][10] = -INFINITY;  s_f[wid][11] = -INFINITY;
    }
    __syncthreads();

    if (threadIdx.x == 0) {
        // iou: two-pointer over the two descending lists; sum in descending
        // order (same float-add sequence as reference top_k -> sum).
        int p0 = 0, p1 = 0;
        float s = 0.0f;
#pragma unroll
        for (int t = 0; t < 10; ++t) {
            const float a = s_f[0][p0], bq = s_f[1][p1];
            if (a >= bq) { s += a; ++p0; } else { s += bq; ++p1; }
        }
        int k = (int)s;                 // trunc (s >= 0)
        if (k < 1) k = 1;
        if (k > 10) k = 10;

        // cost: two-pointer over the two ascending lists; capture t == k-1
        p0 = 0; p1 = 0;
        unsigned long long key = 0;
#pragma unroll
        for (int t = 0; t < 10; ++t) {
            const unsigned long long a = s_e[0][p0], bq = s_e[1][p1];
            unsigned long long cur;
            if (a < bq) { cur = a; ++p0; } else { cur = bq; ++p1; }
            if (t == k - 1) key = cur;
        }
        const unsigned int su = (unsigned int)(key >> 32);
        thrv[r] = __uint_as_float((su & 0x80000000u) ? (su ^ 0x80000000u) : ~su);
        thri[r] = (int)(unsigned int)key;
    }
}

// ---------------------------------------------------------------------------
// kC v2: matching + (>1 matched) argmin fixup, g-split across 4 waves.
// Block: 4 waves over a 64-q tile; wave w owns g in [32w, 32w+32).
// Sole writer of out[b][1].
// ---------------------------------------------------------------------------
__global__ __launch_bounds__(256) void kC2(
    const float* __restrict__ outc,     // cost at [b][0][g][q]
    const float* __restrict__ thrv,
    const int*   __restrict__ thri,
    float* __restrict__ out)            // matching at [b][1][g][q]
{
    const int b  = blockIdx.y;
    const int lq = threadIdx.x & 63;
    const int gh = threadIdx.x >> 6;    // 0..3
    const int q  = blockIdx.x * 64 + lq;

    __shared__ float    s_tv[Gn];
    __shared__ int      s_ti[Gn];
    __shared__ unsigned s_mask[4][64];
    __shared__ float    s_mv[4][64];
    __shared__ int      s_mg[4][64];

    if (threadIdx.x < Gn) {
        s_tv[threadIdx.x] = thrv[b * Gn + threadIdx.x];
        s_ti[threadIdx.x] = thri[b * Gn + threadIdx.x];
    }
    __syncthreads();

    const float* crow = outc + (size_t)(b * 2) * Gn * Qn + q;
    unsigned mask = 0;
    float mv = INFINITY;
    int mg = 0;
    const int gbase = gh * 32;
    if (q < Qn) {
#pragma unroll
        for (int j = 0; j < 32; ++j) {
            const int g = gbase + j;
            const float c = crow[(size_t)g * Qn];
            const bool mt = (c < s_tv[g]) || (c == s_tv[g] && q <= s_ti[g]);
            mask |= (unsigned)mt << j;
            if (c < mv) { mv = c; mg = g; }   // strict: first argmin in chunk
        }
    }
    s_mask[gh][lq] = mask;
    s_mv[gh][lq]   = mv;
    s_mg[gh][lq]   = mg;
    __syncthreads();

    // full-column combine (each thread independently; LDS broadcast-friendly)
    const int cnt = __popc(s_mask[0][lq]) + __popc(s_mask[1][lq])
                  + __popc(s_mask[2][lq]) + __popc(s_mask[3][lq]);
    float bmv = s_mv[0][lq];
    int   bmg = s_mg[0][lq];
#pragma unroll
    for (int h = 1; h < 4; ++h) {
        const float v = s_mv[h][lq];
        if (v < bmv) { bmv = v; bmg = s_mg[h][lq]; }  // ascending h: first argmin
    }
    const bool fix = (cnt > 1);

    if (q < Qn) {
        float* mrow = out + (size_t)(b * 2 + 1) * Gn * Qn + q;
#pragma unroll
        for (int j = 0; j < 32; ++j) {
            const int g = gbase + j;
            const bool bit = (mask >> j) & 1u;
            const bool mt = fix ? (g == bmg) : bit;
            mrow[(size_t)g * Qn] = mt ? 1.0f : 0.0f;
        }
    }
}

// ---------------------------------------------------------------------------
extern "C" void kernel_launch(void* const* d_in, const int* in_sizes, int n_in,
                              void* d_out, int out_size, void* d_ws, size_t ws_size,
                              hipStream_t stream) {
    (void)in_sizes; (void)n_in; (void)out_size;
    const float* logits = (const float*)d_in[0];
    const float* boxes  = (const float*)d_in[1];
    const int*   labels = (const int*)d_in[2];
    const float* tboxes = (const float*)d_in[3];
    float* out = (float*)d_out;

    float* thrv = (float*)((char*)d_ws + kThrvOff);   // [BS*Gn]
    int*   thri = (int*)  ((char*)d_ws + kThriOff);   // [BS*Gn]
    float* F    = (float*)((char*)d_ws + kFOff);      // [BS][Cn][Qn]

    const bool use_f = (ws_size >= kFOff + kFBytes);

    dim3 gF(BS * Gn);                     // one row per block, 2 waves
    if (use_f) {
        dim3 gP(Qn / 32, BS);             // 125 x 16
        kP_focal<<<gP, 256, 0, stream>>>(logits, F);
        kF<true><<<gF, 128, 0, stream>>>(boxes, labels, tboxes, logits, F,
                                         out, thrv, thri);
    } else {
        kF<false><<<gF, 128, 0, stream>>>(boxes, labels, tboxes, logits, nullptr,
                                          out, thrv, thri);
    }

    dim3 gC((Qn + 63) / 64, BS);          // 63 x 16, 4 waves each
    kC2<<<gC, 256, 0, stream>>>(out, thrv, thri, out);
}

// Round 9
// 109.761 us; speedup vs baseline: 2.9734x; 1.0115x over previous
//
#include <hip/hip_runtime.h>
#include <cmath>
#include <cfloat>
#include <climits>

// Match numpy's un-fused f32 arithmetic: matching output is binary, so order
// decisions at the k-th-smallest boundary must agree with the reference.
#pragma clang fp contract(off)

static constexpr int BS = 16;
static constexpr int Qn = 4000;
static constexpr int Cn = 80;
static constexpr int Gn = 128;
static constexpr float kEPS = 1e-8f;

// Replay-invariance rule (learned round 5): every byte of d_out/d_ws holds
// exactly ONE value per call, identical across calls.
//
// d_ws layout: [0,8K) thrv | [8K,16K) thri | [16K, 16K+20.48M) F[b][c][q]

static constexpr size_t kThrvOff = 0;
static constexpr size_t kThriOff = 8 * 1024;
static constexpr size_t kFOff    = 16 * 1024;
static constexpr size_t kFBytes  = (size_t)BS * Cn * Qn * sizeof(float);

__device__ __forceinline__ float focal_cost(float l) {
    const float p = 1.0f / (1.0f + expf(-l));
    const float neg = (0.75f * (p * p)) * (-log1pf(-p + kEPS));
    const float pos = (0.25f * ((1.0f - p) * (1.0f - p))) * (-logf(p + kEPS));
    return pos - neg;
}

// ---------------------------------------------------------------------------
// kP: focal class cost, transposed into d_ws: F[b][c][q].
// ---------------------------------------------------------------------------
__global__ __launch_bounds__(256) void kP_focal(
    const float* __restrict__ logits,   // [BS][Qn][Cn]
    float* __restrict__ F)              // [BS][Cn][Qn]
{
    const int b  = blockIdx.y;
    const int q0 = blockIdx.x * 32;
    const int t  = threadIdx.x;

    __shared__ float s_f[32 * 81];      // [ql][c] padded

    const float* src = logits + ((size_t)b * Qn + q0) * Cn;
#pragma unroll
    for (int i = 0; i < 10; ++i) {
        const int idx = t + i * 256;    // < 2560 = 32*80
        const int ql = idx / 80, c = idx % 80;
        s_f[ql * 81 + c] = focal_cost(src[idx]);
    }
    __syncthreads();

    float* dst = F + (size_t)b * Cn * Qn;
#pragma unroll
    for (int i = 0; i < 10; ++i) {
        const int j = t + i * 256;
        const int c = j >> 5, ql = j & 31;
        dst[(size_t)c * Qn + q0 + ql] = s_f[ql * 81 + c];
    }
}

// ---------------------------------------------------------------------------
// kF v5: fused cost + selection, 4 SPECIALIZED waves per (b,g) row.
// Waves 0,1: cost stream (full geometry + u64 top-10 + cost write).
// Waves 2,3: iou stream (inter/union/iou only + f32 top-10).
// Each wave extracts its sorted-10 via 10x shfl_xor reduce + head pop;
// thread 0 two-pointer merges the 2+2 lists.
// ---------------------------------------------------------------------------
__device__ __forceinline__ unsigned long long pack_ci(float c, int q) {
    const unsigned int u = __float_as_uint(c + 0.0f);       // -0.0 -> +0.0
    const unsigned int s = (u & 0x80000000u) ? ~u : (u | 0x80000000u);
    return ((unsigned long long)s << 32) | (unsigned int)q;
}

__device__ __forceinline__ unsigned long long shfl_xor_u64(unsigned long long v, int m) {
    const int lo = __shfl_xor((int)(unsigned int)v, m, 64);
    const int hi = __shfl_xor((int)(unsigned int)(v >> 32), m, 64);
    return ((unsigned long long)(unsigned int)hi << 32) | (unsigned int)lo;
}

__device__ __forceinline__ void ins10_u64(unsigned long long (&kv)[10], unsigned long long nk) {
    bool le[10];
#pragma unroll
    for (int j = 0; j < 10; ++j) le[j] = (kv[j] < nk);
#pragma unroll
    for (int j = 9; j >= 1; --j)
        kv[j] = le[j] ? kv[j] : (le[j - 1] ? nk : kv[j - 1]);
    if (!le[0]) kv[0] = nk;
}

__device__ __forceinline__ void ins10_desc(float (&iv)[10], float v) {
    bool ge[10];
#pragma unroll
    for (int j = 0; j < 10; ++j) ge[j] = (iv[j] >= v);
#pragma unroll
    for (int j = 9; j >= 1; --j)
        iv[j] = ge[j] ? iv[j] : (ge[j - 1] ? v : iv[j - 1]);
    if (!ge[0]) iv[0] = v;
}

template <bool USE_F>
__global__ __launch_bounds__(256, 8) void kF(
    const float* __restrict__ boxes,    // [BS][Qn][4]
    const int*   __restrict__ labels,   // [BS][Gn]
    const float* __restrict__ tboxes,   // [BS][Gn][4]
    const float* __restrict__ logits,   // [BS][Qn][Cn] (fallback gather)
    const float* __restrict__ F,        // [BS][Cn][Qn] in d_ws (primary)
    float* __restrict__ out,            // cost -> [b][0]
    float* __restrict__ thrv,           // [BS*Gn]
    int*   __restrict__ thri)           // [BS*Gn]
{
    const int lane = threadIdx.x & 63;
    const int wid  = threadIdx.x >> 6;  // 0,1: cost; 2,3: iou
    const int r    = blockIdx.x;
    const int b    = r >> 7;
    const int g    = r & (Gn - 1);

    const float* tb = tboxes + (size_t)r * 4;
    const float tcx = tb[0], tcy = tb[1], tw = tb[2], th = tb[3];
    const float tx0 = tcx - 0.5f * tw, ty0 = tcy - 0.5f * th;
    const float tx1 = tcx + 0.5f * tw, ty1 = tcy + 0.5f * th;
    const float tarea = (tx1 - tx0) * (ty1 - ty0);

    const float4* brow = reinterpret_cast<const float4*>(boxes) + (size_t)b * Qn;

    __shared__ unsigned long long s_e[2][12];
    __shared__ float s_f[2][12];

    if (wid < 2) {
        // ================= cost waves =================
        const int lab = labels[r];
        const float* Frow = USE_F ? (F + ((size_t)b * Cn + lab) * Qn) : nullptr;
        const float* lcol = USE_F ? nullptr : (logits + (size_t)b * Qn * Cn + lab);
        float* crow = out + (size_t)(b * 2) * Gn * Qn + (size_t)g * Qn;

        unsigned long long kv[10];
#pragma unroll
        for (int j = 0; j < 10; ++j) kv[j] = ~0ull;

#pragma unroll
        for (int it = 0; it < 8; ++it) {
            const int q0 = it * 512 + wid * 256 + lane * 4;
            if (q0 < Qn) {
                float cls4[4];
                if (USE_F) {
                    const float4 f4 = *reinterpret_cast<const float4*>(Frow + q0);
                    cls4[0] = f4.x; cls4[1] = f4.y; cls4[2] = f4.z; cls4[3] = f4.w;
                } else {
#pragma unroll
                    for (int e = 0; e < 4; ++e)
                        cls4[e] = focal_cost(lcol[(size_t)(q0 + e) * Cn]);
                }
                float c4[4];
#pragma unroll
                for (int e = 0; e < 4; ++e) {
                    const float cls = cls4[e];
                    const float4 bb = brow[q0 + e];
                    const float cx = bb.x, cy = bb.y, w = bb.z, h = bb.w;
                    const float x0 = cx - 0.5f * w, y0 = cy - 0.5f * h;
                    const float x1 = cx + 0.5f * w, y1 = cy + 0.5f * h;
                    const float area1 = (x1 - x0) * (y1 - y0);
                    const float l1 = ((fabsf(cx - tcx) + fabsf(cy - tcy))
                                      + fabsf(w - tw)) + fabsf(h - th);
                    const float ltx = fmaxf(x0, tx0), lty = fmaxf(y0, ty0);
                    const float rbx = fminf(x1, tx1), rby = fminf(y1, ty1);
                    const float iw = fmaxf(rbx - ltx, 0.0f), ih = fmaxf(rby - lty, 0.0f);
                    const float inter = iw * ih;
                    const float uni = (area1 + tarea) - inter;
                    const float iou = inter / (uni + kEPS);
                    const float cltx = fminf(x0, tx0), clty = fminf(y0, ty0);
                    const float crbx = fmaxf(x1, tx1), crby = fmaxf(y1, ty1);
                    const float cw = fmaxf(crbx - cltx, 0.0f), ch = fmaxf(crby - clty, 0.0f);
                    const float areac = cw * ch;
                    const float giou = iou - (areac - uni) / (areac + kEPS);

                    const float cost = (5.0f * l1 + 2.0f * cls) + 2.0f * (-giou);
                    c4[e] = cost;
                    ins10_u64(kv, pack_ci(cost, q0 + e));
                }
                float4 cv4; cv4.x = c4[0]; cv4.y = c4[1]; cv4.z = c4[2]; cv4.w = c4[3];
                *reinterpret_cast<float4*>(crow + q0) = cv4;
            }
        }

        // extraction: 10 smallest unique u64 keys
        unsigned long long e[10];
#pragma unroll
        for (int t = 0; t < 10; ++t) {
            unsigned long long m = kv[0];
#pragma unroll
            for (int d = 1; d <= 32; d <<= 1) {
                const unsigned long long o = shfl_xor_u64(m, d);
                if (o < m) m = o;
            }
            e[t] = m;                       // all lanes agree
            if (kv[0] == m) {               // unique keys -> exactly one owner
#pragma unroll
                for (int j = 0; j < 9; ++j) kv[j] = kv[j + 1];
                kv[9] = ~0ull;
            }
        }
        if (lane == 0) {
#pragma unroll
            for (int j = 0; j < 10; ++j) s_e[wid][j] = e[j];
            s_e[wid][10] = ~0ull; s_e[wid][11] = ~0ull;
        }
    } else {
        // ================= iou waves =================
        float iv[10];
#pragma unroll
        for (int j = 0; j < 10; ++j) iv[j] = -INFINITY;

#pragma unroll
        for (int it = 0; it < 8; ++it) {
            const int q0 = it * 512 + (wid - 2) * 256 + lane * 4;
            if (q0 < Qn) {
#pragma unroll
                for (int e = 0; e < 4; ++e) {
                    const float4 bb = brow[q0 + e];
                    const float x0 = bb.x - 0.5f * bb.z, y0 = bb.y - 0.5f * bb.w;
                    const float x1 = bb.x + 0.5f * bb.z, y1 = bb.y + 0.5f * bb.w;
                    const float area1 = (x1 - x0) * (y1 - y0);
                    const float ltx = fmaxf(x0, tx0), lty = fmaxf(y0, ty0);
                    const float rbx = fminf(x1, tx1), rby = fminf(y1, ty1);
                    const float iw = fmaxf(rbx - ltx, 0.0f), ih = fmaxf(rby - lty, 0.0f);
                    const float inter = iw * ih;
                    const float uni = (area1 + tarea) - inter;
                    const float iou = inter / (uni + kEPS);
                    ins10_desc(iv, iou);
                }
            }
        }

        // extraction: 10 largest ious (ties: pop first owner only)
        float f[10];
#pragma unroll
        for (int t = 0; t < 10; ++t) {
            float m = iv[0];
#pragma unroll
            for (int d = 1; d <= 32; d <<= 1)
                m = fmaxf(m, __shfl_xor(m, d, 64));
            f[t] = m;
            const bool own0 = (iv[0] == m);
            const unsigned long long bal = __ballot(own0);
            if (own0 && lane == __ffsll((long long)bal) - 1) {
#pragma unroll
                for (int j = 0; j < 9; ++j) iv[j] = iv[j + 1];
                iv[9] = -INFINITY;
            }
        }
        if (lane == 0) {
#pragma unroll
            for (int j = 0; j < 10; ++j) s_f[wid - 2][j] = f[j];
            s_f[wid - 2][10] = -INFINITY; s_f[wid - 2][11] = -INFINITY;
        }
    }

    __syncthreads();

    if (threadIdx.x == 0) {
        // iou: two-pointer over the two descending lists; sum in descending
        // order (same float-add sequence as reference top_k -> sum).
        int p0 = 0, p1 = 0;
        float s = 0.0f;
#pragma unroll
        for (int t = 0; t < 10; ++t) {
            const float a = s_f[0][p0], bq = s_f[1][p1];
            if (a >= bq) { s += a; ++p0; } else { s += bq; ++p1; }
        }
        int k = (int)s;                 // trunc (s >= 0)
        if (k < 1) k = 1;
        if (k > 10) k = 10;

        // cost: two-pointer over the two ascending lists; capture t == k-1
        p0 = 0; p1 = 0;
        unsigned long long key = 0;
#pragma unroll
        for (int t = 0; t < 10; ++t) {
            const unsigned long long a = s_e[0][p0], bq = s_e[1][p1];
            unsigned long long cur;
            if (a < bq) { cur = a; ++p0; } else { cur = bq; ++p1; }
            if (t == k - 1) key = cur;
        }
        const unsigned int su = (unsigned int)(key >> 32);
        thrv[r] = __uint_as_float((su & 0x80000000u) ? (su ^ 0x80000000u) : ~su);
        thri[r] = (int)(unsigned int)key;
    }
}

// ---------------------------------------------------------------------------
// kC v2: matching + (>1 matched) argmin fixup, g-split across 4 waves.
// Block: 4 waves over a 64-q tile; wave w owns g in [32w, 32w+32).
// Sole writer of out[b][1].
// ---------------------------------------------------------------------------
__global__ __launch_bounds__(256) void kC2(
    const float* __restrict__ outc,     // cost at [b][0][g][q]
    const float* __restrict__ thrv,
    const int*   __restrict__ thri,
    float* __restrict__ out)            // matching at [b][1][g][q]
{
    const int b  = blockIdx.y;
    const int lq = threadIdx.x & 63;
    const int gh = threadIdx.x >> 6;    // 0..3
    const int q  = blockIdx.x * 64 + lq;

    __shared__ float    s_tv[Gn];
    __shared__ int      s_ti[Gn];
    __shared__ unsigned s_mask[4][64];
    __shared__ float    s_mv[4][64];
    __shared__ int      s_mg[4][64];

    if (threadIdx.x < Gn) {
        s_tv[threadIdx.x] = thrv[b * Gn + threadIdx.x];
        s_ti[threadIdx.x] = thri[b * Gn + threadIdx.x];
    }
    __syncthreads();

    const float* crow = outc + (size_t)(b * 2) * Gn * Qn + q;
    unsigned mask = 0;
    float mv = INFINITY;
    int mg = 0;
    const int gbase = gh * 32;
    if (q < Qn) {
#pragma unroll
        for (int j = 0; j < 32; ++j) {
            const int g = gbase + j;
            const float c = crow[(size_t)g * Qn];
            const bool mt = (c < s_tv[g]) || (c == s_tv[g] && q <= s_ti[g]);
            mask |= (unsigned)mt << j;
            if (c < mv) { mv = c; mg = g; }   // strict: first argmin in chunk
        }
    }
    s_mask[gh][lq] = mask;
    s_mv[gh][lq]   = mv;
    s_mg[gh][lq]   = mg;
    __syncthreads();

    // full-column combine (each thread independently; LDS broadcast-friendly)
    const int cnt = __popc(s_mask[0][lq]) + __popc(s_mask[1][lq])
                  + __popc(s_mask[2][lq]) + __popc(s_mask[3][lq]);
    float bmv = s_mv[0][lq];
    int   bmg = s_mg[0][lq];
#pragma unroll
    for (int h = 1; h < 4; ++h) {
        const float v = s_mv[h][lq];
        if (v < bmv) { bmv = v; bmg = s_mg[h][lq]; }  // ascending h: first argmin
    }
    const bool fix = (cnt > 1);

    if (q < Qn) {
        float* mrow = out + (size_t)(b * 2 + 1) * Gn * Qn + q;
#pragma unroll
        for (int j = 0; j < 32; ++j) {
            const int g = gbase + j;
            const bool bit = (mask >> j) & 1u;
            const bool mt = fix ? (g == bmg) : bit;
            mrow[(size_t)g * Qn] = mt ? 1.0f : 0.0f;
        }
    }
}

// ---------------------------------------------------------------------------
extern "C" void kernel_launch(void* const* d_in, const int* in_sizes, int n_in,
                              void* d_out, int out_size, void* d_ws, size_t ws_size,
                              hipStream_t stream) {
    (void)in_sizes; (void)n_in; (void)out_size;
    const float* logits = (const float*)d_in[0];
    const float* boxes  = (const float*)d_in[1];
    const int*   labels = (const int*)d_in[2];
    const float* tboxes = (const float*)d_in[3];
    float* out = (float*)d_out;

    float* thrv = (float*)((char*)d_ws + kThrvOff);   // [BS*Gn]
    int*   thri = (int*)  ((char*)d_ws + kThriOff);   // [BS*Gn]
    float* F    = (float*)((char*)d_ws + kFOff);      // [BS][Cn][Qn]

    const bool use_f = (ws_size >= kFOff + kFBytes);

    dim3 gF(BS * Gn);                     // one row per block, 4 waves
    if (use_f) {
        dim3 gP(Qn / 32, BS);             // 125 x 16
        kP_focal<<<gP, 256, 0, stream>>>(logits, F);
        kF<true><<<gF, 256, 0, stream>>>(boxes, labels, tboxes, logits, F,
                                         out, thrv, thri);
    } else {
        kF<false><<<gF, 256, 0, stream>>>(boxes, labels, tboxes, logits, nullptr,
                                          out, thrv, thri);
    }

    dim3 gC((Qn + 63) / 64, BS);          // 63 x 16, 4 waves each
    kC2<<<gC, 256, 0, stream>>>(out, thrv, thri, out);
}